// Round 5
// baseline (653.083 us; speedup 1.0000x reference)
//
#include <hip/hip_runtime.h>

// MMHSA Matryoshka attention, B=4, S=2048, D=2048, slices {512,1024,1536,2048}.
// Big GEMMs (QKV proj, final proj): 256^2-tile deep-pipelined bf16 MFMA kernel.
//   Ring-4 of BK=32 LDS slots; per K-tile: stage(t+3) -> vmcnt(12) -> barrier ->
//   12 ds_read_b128 -> 32 MFMA (setprio) -> barrier. XOR bank-swizzle (0 conflicts),
//   XCD-chunked decode with n-fastest/m-slowest (A-panels L2-resident per XCD).
// Attention: 2-pass snapshot QK sweep + bf16 softmax (write-truncated) + 128^2 PV.
//
// Workspace (R = 32 MiB, 6R = 201.3 MB):
//   [0,R):    xb (bf16 x)          -> attn scratch for slice 1
//   [R,2R):   wqT wkT wvT woT bf16
//   [2R,3R):  q   [3R,4R): k   [4R,5R): v -> o   [5R,6R): vT
// bf16 snapshots live in d_out (slot0/slot1) until the final GEMM.

typedef __attribute__((ext_vector_type(8))) short bf16x8;
typedef __attribute__((ext_vector_type(4))) float f32x4;
typedef unsigned short u16;
typedef unsigned int u32;

__device__ __forceinline__ u16 f2bf(float f) {
  union { float f; u32 u; } v; v.f = f;
  u32 r = v.u + 0x7fffu + ((v.u >> 16) & 1u);
  return (u16)(r >> 16);
}
__device__ __forceinline__ float bf2f(u16 b) {
  union { u32 u; float f; } v; v.u = ((u32)b) << 16;
  return v.f;
}
struct alignas(16) U16x8 { u16 v[8]; };

#define GLDS(gp, lp)                                                      \
  __builtin_amdgcn_global_load_lds(                                       \
      (const __attribute__((address_space(1))) void*)(gp),                \
      (__attribute__((address_space(3))) void*)(lp), 16, 0, 0)

// ---------------- conversion / transpose kernels ----------------

__global__ __launch_bounds__(256) void conv_f32_bf16(const float* __restrict__ in,
                                                     u16* __restrict__ out) {
  size_t i = ((size_t)blockIdx.x * 256 + threadIdx.x) * 8;
  float4 a = *(const float4*)(in + i);
  float4 b = *(const float4*)(in + i + 4);
  U16x8 w;
  w.v[0] = f2bf(a.x); w.v[1] = f2bf(a.y); w.v[2] = f2bf(a.z); w.v[3] = f2bf(a.w);
  w.v[4] = f2bf(b.x); w.v[5] = f2bf(b.y); w.v[6] = f2bf(b.z); w.v[7] = f2bf(b.w);
  *(U16x8*)(out + i) = w;
}

__global__ __launch_bounds__(256) void transpose_conv4(const float* __restrict__ W0,
                                                       const float* __restrict__ W1,
                                                       const float* __restrict__ W2,
                                                       const float* __restrict__ W3,
                                                       u16* __restrict__ out) {
  const int D = 2048;
  const float* in = (blockIdx.z == 0) ? W0 : (blockIdx.z == 1) ? W1
                  : (blockIdx.z == 2) ? W2 : W3;
  u16* o = out + (size_t)blockIdx.z * D * D;
  __shared__ float t[32][33];
  int bx = blockIdx.x * 32, by = blockIdx.y * 32;
  int tx = threadIdx.x & 31, ty = threadIdx.x >> 5;
#pragma unroll
  for (int i = 0; i < 32; i += 8)
    t[ty + i][tx] = in[(size_t)(by + ty + i) * D + bx + tx];
  __syncthreads();
#pragma unroll
  for (int i = 0; i < 32; i += 8)
    o[(size_t)(bx + ty + i) * D + by + tx] = f2bf(t[tx][ty + i]);
}

__global__ __launch_bounds__(256) void transpose_bf16(const u16* __restrict__ in,
                                                      u16* __restrict__ out) {
  const int D = 2048;
  size_t zoff = (size_t)blockIdx.z * D * D;
  in += zoff; out += zoff;
  __shared__ u16 t[32][34];
  int bx = blockIdx.x * 32, by = blockIdx.y * 32;
  int tx = threadIdx.x & 31, ty = threadIdx.x >> 5;
#pragma unroll
  for (int i = 0; i < 32; i += 8)
    t[ty + i][tx] = in[(size_t)(by + ty + i) * D + bx + tx];
  __syncthreads();
#pragma unroll
  for (int i = 0; i < 32; i += 8)
    out[(size_t)(bx + ty + i) * D + by + tx] = t[tx][ty + i];
}

// ============ 256^2 deep-pipelined NT GEMM: C[M,N] = A[M,K] @ B[N,K]^T ============
// 512 threads, 8 waves (2M x 4N), per-wave output 128x64. Ring-4 of BK=32 K-tiles
// (4 x 32 KB = 128 KB LDS). Per K-tile: stage t+3, vmcnt(12) [3 tiles in flight],
// barrier, 12 ds_read_b128, 32 MFMA under setprio, barrier.
// LDS bank swizzle: 16B slot s at row r holds global slot s ^ ((r>>1)&3).
// Requires K % 32 == 0, K/32 >= 4, M,N multiples of 256, grid.x % 8 == 0.
template <bool OUT_BF16>
__global__ __launch_bounds__(512, 2) void gemm256(
    const u16* __restrict__ A, int lda,
    const u16* __restrict__ B, int ldb,
    void* __restrict__ Cv, int ldc,
    int K, int nmat, int ntn, long long sBm, long long sCm) {
  extern __shared__ char smem[];
  u16* const As = (u16*)smem;             // [4][256*32] u16 (16 KB per slot)
  u16* const Bs = (u16*)(smem + 65536);

  // XCD-chunked decode: n fastest, then mat, then m (per-XCD A-panels stay in L2)
  u32 wg = blockIdx.x;
  u32 nchunk = gridDim.x >> 3;
  u32 swz = (wg & 7u) * nchunk + (wg >> 3);
  const int n0 = (int)(swz % (u32)ntn) * 256;
  u32 t2 = swz / (u32)ntn;
  const int mat = (int)(t2 % (u32)nmat);
  const int m0 = (int)(t2 / (u32)nmat) * 256;

  B += (size_t)mat * sBm;

  const int tid = threadIdx.x;
  const int lane = tid & 63, wave = tid >> 6;
  const int wm = (wave >> 2) * 128;       // 0 or 128
  const int wn = (wave & 3) * 64;         // 0,64,128,192
  const int fr = lane & 15, kgrp = lane >> 4;
  const u32 lo = (u32)(wave * 1024);      // wave-uniform LDS chunk for staging

  // staging map: thread covers LDS row srow (and srow+128), 16B slot (tid&3);
  // pre-swizzled global source slot ssl so LDS stays linear (rule #21)
  const int srow = tid >> 2;
  const int ssl = (tid & 3) ^ ((srow >> 1) & 3);
  const u16* gA0 = A + (size_t)(m0 + srow) * lda + ssl * 8;
  const u16* gA1 = gA0 + (size_t)128 * lda;
  const u16* gB0 = B + (size_t)(n0 + srow) * ldb + ssl * 8;
  const u16* gB1 = gB0 + (size_t)128 * ldb;

  // ds_read swizzled k-offset (u16 units): slot kgrp at row -> pos kgrp ^ ((row>>1)&3)
  const int koe = (kgrp ^ ((fr >> 1) & 3)) * 8;

#define STG(slot, kOff) do {                                              \
    char* la = (char*)As + (slot) * 16384 + lo;                           \
    char* lb = (char*)Bs + (slot) * 16384 + lo;                           \
    GLDS(gA0 + (kOff), la);                                               \
    GLDS(gA1 + (kOff), la + 8192);                                        \
    GLDS(gB0 + (kOff), lb);                                               \
    GLDS(gB1 + (kOff), lb + 8192);                                        \
  } while (0)

  f32x4 acc[8][4];
#pragma unroll
  for (int m = 0; m < 8; ++m)
#pragma unroll
    for (int n = 0; n < 4; ++n)
#pragma unroll
      for (int j = 0; j < 4; ++j) acc[m][n][j] = 0.f;

  const int NT = K >> 5;
  // prologue: stage tiles 0,1,2 (12 loads in flight)
  STG(0, 0);
  STG(1, 32);
  STG(2, 64);

  for (int tt = 0; tt < NT; ++tt) {
    if (tt + 3 < NT) STG((tt + 3) & 3, (tt + 3) * 32);
    // allow tiles t+1..t+3 in flight; drain tile t (wave-uniform branch)
    const int ou = NT - 1 - tt;
    if (ou >= 3)      asm volatile("s_waitcnt vmcnt(12)" ::: "memory");
    else if (ou == 2) asm volatile("s_waitcnt vmcnt(8)" ::: "memory");
    else if (ou == 1) asm volatile("s_waitcnt vmcnt(4)" ::: "memory");
    else              asm volatile("s_waitcnt vmcnt(0)" ::: "memory");
    __builtin_amdgcn_s_barrier();   // all waves' tile-t stages visible

    const u16* as = As + (tt & 3) * 8192;   // u16 units
    const u16* bs = Bs + (tt & 3) * 8192;
    bf16x8 af[8], bfr[4];
#pragma unroll
    for (int n = 0; n < 4; ++n)
      bfr[n] = *(const bf16x8*)&bs[((wn + n * 16 + fr) << 5) + koe];
#pragma unroll
    for (int m = 0; m < 8; ++m)
      af[m] = *(const bf16x8*)&as[((wm + m * 16 + fr) << 5) + koe];

    __builtin_amdgcn_s_setprio(1);
#pragma unroll
    for (int m = 0; m < 8; ++m)
#pragma unroll
      for (int n = 0; n < 4; ++n)
        acc[m][n] = __builtin_amdgcn_mfma_f32_16x16x32_bf16(af[m], bfr[n],
                                                            acc[m][n], 0, 0, 0);
    __builtin_amdgcn_s_setprio(0);
    __builtin_amdgcn_s_barrier();   // reads done before next iter's STG overwrites
  }
#undef STG

  // epilogue: C/D layout col = lane&15, row = (lane>>4)*4 + j
  const int cl = lane & 15, rb = (lane >> 4) * 4;
  if (OUT_BF16) {
    u16* C = (u16*)Cv + (size_t)mat * sCm;
#pragma unroll
    for (int m = 0; m < 8; ++m)
#pragma unroll
      for (int n = 0; n < 4; ++n)
#pragma unroll
        for (int j = 0; j < 4; ++j)
          C[(size_t)(m0 + wm + m * 16 + rb + j) * ldc + (n0 + wn + n * 16 + cl)] =
              f2bf(acc[m][n][j]);
  } else {
    float* C = (float*)Cv + (size_t)mat * sCm;
#pragma unroll
    for (int m = 0; m < 8; ++m)
#pragma unroll
      for (int n = 0; n < 4; ++n)
#pragma unroll
        for (int j = 0; j < 4; ++j)
          C[(size_t)(m0 + wm + m * 16 + rb + j) * ldc + (n0 + wn + n * 16 + cl)] =
              acc[m][n][j];
  }
}

// ---------------- staging macro for 128^2 kernels (128x32 bf16 tile) ----------------
#define STAGE4(Abuf, Bbuf, kOff)                                                       \
  do {                                                                                 \
    GLDS(ga0 + (kOff), (char*)(Abuf) + lo);                                            \
    GLDS(ga1 + (kOff), (char*)(Abuf) + lo + 4096);                                     \
    GLDS(gb0 + (kOff), (char*)(Bbuf) + lo);                                            \
    GLDS(gb1 + (kOff), (char*)(Bbuf) + lo + 4096);                                     \
  } while (0)

// ---------------- 128^2 NT GEMM (m97 structure) for PV ----------------
// kmode: 0 plain, 2 causal PV (truncate K at m0+128).
template <bool OUT_BF16>
__global__ __launch_bounds__(256) void gemm_nt(
    const u16* __restrict__ A, long long sA, int lda,
    const u16* __restrict__ B, long long sB, int ldb,
    void* __restrict__ Cv, long long sC, int ldc,
    int K, int kmode) {
  const int n0 = blockIdx.x * 128, m0 = blockIdx.y * 128;
  const int z = blockIdx.z;
  const int kEnd = (kmode == 2) ? (m0 + 128) : K;

  A += (size_t)z * sA;
  B += (size_t)z * sB;

  __shared__ alignas(16) u16 As[2][128 * 32];
  __shared__ alignas(16) u16 Bs[2][128 * 32];

  const int tid = threadIdx.x;
  const int lane = tid & 63, wave = tid >> 6;
  const int wm = (wave >> 1) * 64, wn = (wave & 1) * 64;
  const int fr = lane & 15, kc = (lane >> 4) * 8;

  const u16* ga0 = A + (size_t)(m0 + (tid >> 2)) * lda + (tid & 3) * 8;
  const u16* ga1 = ga0 + (size_t)64 * lda;
  const u16* gb0 = B + (size_t)(n0 + (tid >> 2)) * ldb + (tid & 3) * 8;
  const u16* gb1 = gb0 + (size_t)64 * ldb;
  const u32 lo = (u32)(wave * 1024);

  f32x4 acc[4][4];
#pragma unroll
  for (int m = 0; m < 4; ++m)
#pragma unroll
    for (int n = 0; n < 4; ++n)
#pragma unroll
      for (int j = 0; j < 4; ++j) acc[m][n][j] = 0.f;

  const int nt = kEnd >> 5;
  STAGE4(&As[0][0], &Bs[0][0], 0);
  for (int t = 0; t < nt; ++t) {
    __syncthreads();
    if (t + 1 < nt) STAGE4(&As[(t + 1) & 1][0], &Bs[(t + 1) & 1][0], (t + 1) * 32);
    const u16* as = &As[t & 1][0];
    const u16* bs = &Bs[t & 1][0];
    bf16x8 af[4], bfr[4];
#pragma unroll
    for (int m = 0; m < 4; ++m)
      af[m] = *(const bf16x8*)&as[(wm + m * 16 + fr) * 32 + kc];
#pragma unroll
    for (int n = 0; n < 4; ++n)
      bfr[n] = *(const bf16x8*)&bs[(wn + n * 16 + fr) * 32 + kc];
#pragma unroll
    for (int m = 0; m < 4; ++m)
#pragma unroll
      for (int n = 0; n < 4; ++n)
        acc[m][n] = __builtin_amdgcn_mfma_f32_16x16x32_bf16(af[m], bfr[n],
                                                            acc[m][n], 0, 0, 0);
  }

  const int col = lane & 15, rb = (lane >> 4) * 4;
  if (OUT_BF16) {
    u16* C = (u16*)Cv + (size_t)z * sC;
#pragma unroll
    for (int m = 0; m < 4; ++m)
#pragma unroll
      for (int n = 0; n < 4; ++n)
#pragma unroll
        for (int j = 0; j < 4; ++j)
          C[(size_t)(m0 + wm + m * 16 + rb + j) * ldc + (n0 + wn + n * 16 + col)] =
              f2bf(acc[m][n][j]);
  } else {
    float* C = (float*)Cv + (size_t)z * sC;
#pragma unroll
    for (int m = 0; m < 4; ++m)
#pragma unroll
      for (int n = 0; n < 4; ++n)
#pragma unroll
        for (int j = 0; j < 4; ++j)
          C[(size_t)(m0 + wm + m * 16 + rb + j) * ldc + (n0 + wn + n * 16 + col)] =
              acc[m][n][j];
  }
}

// ---------------- snapshot QK sweep (K=1024 per pass, 128^2 tiles) ----------------
__global__ __launch_bounds__(256) void qk_mega(
    const u16* __restrict__ A, const u16* __restrict__ B,
    u16* __restrict__ snapA, u16* __restrict__ snapB,
    float scaleA, float scaleB,
    const u16* __restrict__ initSrc, float initScale) {
  const int lda = 2048;
  const int m0 = blockIdx.y * 128, n0 = blockIdx.x * 128;
  if (n0 >= m0 + 128) return;  // fully masked tile
  const size_t zWE = (size_t)blockIdx.z * 4194304ull;

  __shared__ alignas(16) u16 As[2][128 * 32];
  __shared__ alignas(16) u16 Bs[2][128 * 32];

  const int tid = threadIdx.x;
  const int lane = tid & 63, wave = tid >> 6;
  const int wm = (wave >> 1) * 64, wn = (wave & 1) * 64;
  const int fr = lane & 15, kc = (lane >> 4) * 8;
  const int col = lane & 15, rb = (lane >> 4) * 4;

  const u16* ga0 = A + zWE + (size_t)(m0 + (tid >> 2)) * lda + (tid & 3) * 8;
  const u16* ga1 = ga0 + (size_t)64 * lda;
  const u16* gb0 = B + zWE + (size_t)(n0 + (tid >> 2)) * lda + (tid & 3) * 8;
  const u16* gb1 = gb0 + (size_t)64 * lda;
  const u32 lo = (u32)(wave * 1024);

  f32x4 acc[4][4];
  if (initSrc) {
    const u16* ip = initSrc + zWE;
#pragma unroll
    for (int m = 0; m < 4; ++m)
#pragma unroll
      for (int n = 0; n < 4; ++n)
#pragma unroll
        for (int j = 0; j < 4; ++j)
          acc[m][n][j] = bf2f(ip[(size_t)(m0 + wm + m * 16 + rb + j) * 2048 +
                                 (n0 + wn + n * 16 + col)]) * initScale;
  } else {
#pragma unroll
    for (int m = 0; m < 4; ++m)
#pragma unroll
      for (int n = 0; n < 4; ++n)
#pragma unroll
        for (int j = 0; j < 4; ++j) acc[m][n][j] = 0.f;
  }

#define SNAPW(ptr, scl)                                                                \
  do {                                                                                 \
    u16* sp = (ptr) + zWE;                                                             \
    _Pragma("unroll") for (int m = 0; m < 4; ++m)                                      \
    _Pragma("unroll") for (int n = 0; n < 4; ++n)                                      \
    _Pragma("unroll") for (int j = 0; j < 4; ++j)                                      \
        sp[(size_t)(m0 + wm + m * 16 + rb + j) * 2048 + (n0 + wn + n * 16 + col)] =    \
            f2bf(acc[m][n][j] * (scl));                                                \
  } while (0)

  STAGE4(&As[0][0], &Bs[0][0], 0);
  for (int t = 0; t < 32; ++t) {
    __syncthreads();
    if (t + 1 < 32) STAGE4(&As[(t + 1) & 1][0], &Bs[(t + 1) & 1][0], (t + 1) * 32);
    const u16* as = &As[t & 1][0];
    const u16* bs = &Bs[t & 1][0];
    bf16x8 af[4], bfr[4];
#pragma unroll
    for (int m = 0; m < 4; ++m)
      af[m] = *(const bf16x8*)&as[(wm + m * 16 + fr) * 32 + kc];
#pragma unroll
    for (int n = 0; n < 4; ++n)
      bfr[n] = *(const bf16x8*)&bs[(wn + n * 16 + fr) * 32 + kc];
#pragma unroll
    for (int m = 0; m < 4; ++m)
#pragma unroll
      for (int n = 0; n < 4; ++n)
        acc[m][n] = __builtin_amdgcn_mfma_f32_16x16x32_bf16(af[m], bfr[n],
                                                            acc[m][n], 0, 0, 0);
    if (t == 15) SNAPW(snapA, scaleA);  // K=512 prefix done
  }
  SNAPW(snapB, scaleB);
#undef SNAPW
}

// ---------------- causal row softmax on scaled bf16 logits ----------------
// Writes only cols [0, roundup128(r+1)) — PV never reads beyond its kEnd.
__global__ __launch_bounds__(256) void softmax_causal(const u16* __restrict__ in,
                                                      u16* __restrict__ out) {
  const int S = 2048;
  const size_t WEz = (size_t)S * S * blockIdx.y;
  const int r = blockIdx.x;
  const int tid = threadIdx.x;
  const int lane = tid & 63, wave = tid >> 6;
  const int c0 = tid * 8;
  const int nvalid = r + 1;
  const int nwrite = (r & ~127) + 128;
  const u16* rowp = in + WEz + (size_t)r * S;

  float x[8];
  if (c0 < nvalid) {
    U16x8 a = *(const U16x8*)(rowp + c0);
#pragma unroll
    for (int i = 0; i < 8; ++i) x[i] = bf2f(a.v[i]);
  } else {
#pragma unroll
    for (int i = 0; i < 8; ++i) x[i] = 0.f;
  }

  float mx = -3e38f;
#pragma unroll
  for (int i = 0; i < 8; ++i)
    if (c0 + i < nvalid) mx = fmaxf(mx, x[i]);
#pragma unroll
  for (int off = 32; off > 0; off >>= 1) mx = fmaxf(mx, __shfl_xor(mx, off));
  __shared__ float redm[4], reds[4];
  if (lane == 0) redm[wave] = mx;
  __syncthreads();
  mx = fmaxf(fmaxf(redm[0], redm[1]), fmaxf(redm[2], redm[3]));

  float e[8], sum = 0.f;
#pragma unroll
  for (int i = 0; i < 8; ++i) {
    e[i] = (c0 + i < nvalid) ? __expf(x[i] - mx) : 0.f;
    sum += e[i];
  }
#pragma unroll
  for (int off = 32; off > 0; off >>= 1) sum += __shfl_xor(sum, off);
  if (lane == 0) reds[wave] = sum;
  __syncthreads();
  sum = reds[0] + reds[1] + reds[2] + reds[3];
  float inv = 1.f / sum;

  if (c0 < nwrite) {
    U16x8 w;
#pragma unroll
    for (int i = 0; i < 8; ++i) w.v[i] = f2bf(e[i] * inv);
    *(U16x8*)(out + WEz + (size_t)r * S + c0) = w;
  }
}

// ---------------- launcher ----------------
extern "C" void kernel_launch(void* const* d_in, const int* in_sizes, int n_in,
                              void* d_out, int out_size, void* d_ws, size_t ws_size,
                              hipStream_t stream) {
  (void)in_sizes; (void)n_in; (void)out_size; (void)ws_size;
  const float* x  = (const float*)d_in[0];
  // d_in[1] is the boolean causal mask; causality is hard-coded.
  const float* Wq = (const float*)d_in[2];
  const float* Wk = (const float*)d_in[3];
  const float* Wv = (const float*)d_in[4];
  const float* Wo = (const float*)d_in[5];
  float* out = (float*)d_out;

  char* w = (char*)d_ws;
  const size_t R  = 33554432ull;
  const long long WE = 4194304LL;   // 2048*2048 elems

  u16* xb  = (u16*)(w);
  u16* wT  = (u16*)(w + R);
  u16* wqT = wT;
  u16* woT = wT + 3 * WE;
  u16* q   = (u16*)(w + 2 * R);
  u16* kk  = (u16*)(w + 3 * R);
  u16* v   = (u16*)(w + 4 * R);
  u16* vT  = (u16*)(w + 5 * R);
  u16* o   = v;                      // v dead after transpose
  u16* attnx = xb;                   // xb dead after projections
  u16* slot0 = (u16*)d_out;          // 16.8M elems (4 batches x S x S bf16)
  u16* slot1 = slot0 + 16777216ull;  // second half of d_out

  const float sc0 = 1.0f / sqrtf(512.0f);
  const float sc1 = 1.0f / sqrtf(1024.0f);
  const float sc2 = 1.0f / sqrtf(1536.0f);
  const float sc3 = 1.0f / sqrtf(2048.0f);

  // allow 128 KB dynamic LDS on the big-tile GEMM (deterministic, capture-safe)
  hipFuncSetAttribute(reinterpret_cast<const void*>(&gemm256<true>),
                      hipFuncAttributeMaxDynamicSharedMemorySize, 131072);
  hipFuncSetAttribute(reinterpret_cast<const void*>(&gemm256<false>),
                      hipFuncAttributeMaxDynamicSharedMemorySize, 131072);

  // 1) x -> bf16; weights -> transposed bf16
  conv_f32_bf16<<<8192, 256, 0, stream>>>(x, xb);
  transpose_conv4<<<dim3(64, 64, 4), 256, 0, stream>>>(Wq, Wk, Wv, Wo, wT);
  // 2) fused q,k,v projection: M=8192, per-mat N=2048, K=2048, 3 mats
  gemm256<true><<<dim3(768), 512, 131072, stream>>>(
      xb, 2048, wqT, 2048, q, 2048, 2048, 3, 8, WE, 16777216LL);
  // 3) v -> vT
  transpose_bf16<<<dim3(64, 64, 4), 256, 0, stream>>>(v, vT);
  // 4) pass A: K=0..1024, snapshots -> slot0 (slice0), slot1 (slice1)
  qk_mega<<<dim3(16, 16, 4), 256, 0, stream>>>(q, kk, slot0, slot1, sc0, sc1,
                                               nullptr, 0.f);
  softmax_causal<<<dim3(2048, 4), 256, 0, stream>>>(slot0, slot0);
  gemm_nt<true><<<dim3(4, 16, 4), 256, 0, stream>>>(
      slot0, WE, 2048, vT, WE, 2048, o, WE, 2048, 2048, 2);
  softmax_causal<<<dim3(2048, 4), 256, 0, stream>>>(slot1, attnx);
  gemm_nt<true><<<dim3(4, 16, 4), 256, 0, stream>>>(
      attnx, WE, 2048, vT + 1048576, WE, 2048, o + 512, WE, 2048, 2048, 2);
  // 5) pass B: K=1024..2048, init from slot1 (* sqrt(1024)), snapshots slices 2,3
  qk_mega<<<dim3(16, 16, 4), 256, 0, stream>>>(q + 1024, kk + 1024, slot0, slot1,
                                               sc2, sc3, slot1, 32.0f);
  softmax_causal<<<dim3(2048, 4), 256, 0, stream>>>(slot0, slot0);
  gemm_nt<true><<<dim3(4, 16, 4), 256, 0, stream>>>(
      slot0, WE, 2048, vT + 2 * 1048576, WE, 2048, o + 1024, WE, 2048, 2048, 2);
  softmax_causal<<<dim3(2048, 4), 256, 0, stream>>>(slot1, slot1);
  gemm_nt<true><<<dim3(4, 16, 4), 256, 0, stream>>>(
      slot1, WE, 2048, vT + 3 * 1048576, WE, 2048, o + 1536, WE, 2048, 2048, 2);
  // 6) out = o @ Wo: M=8192, N=2048, K=2048
  gemm256<false><<<dim3(256), 512, 131072, stream>>>(
      o, 2048, woT, 2048, out, 2048, 2048, 1, 8, 0LL, 0LL);
}

// Round 6
// 643.585 us; speedup vs baseline: 1.0148x; 1.0148x over previous
//
#include <hip/hip_runtime.h>

// MMHSA Matryoshka attention, B=4, S=2048, D=2048, slices {512,1024,1536,2048}.
// Big GEMMs (QKV proj, final proj): 256^2-tile bf16 MFMA kernel, ring-4 BK=32
//   LDS slots, REGISTER-PIPELINED fragments (read tile t+1 during tile t's MFMA),
//   one barrier per K-tile, counted vmcnt/lgkmcnt, setprio, XOR bank-swizzle.
// Attention: 2-pass snapshot QK sweep + bf16 softmax (write-truncated) + 128^2 PV.
//
// Workspace (R = 32 MiB, 6R = 201.3 MB):
//   [0,R):    xb (bf16 x)          -> attn scratch for slice 1
//   [R,2R):   wqT wkT wvT woT bf16
//   [2R,3R):  q   [3R,4R): k   [4R,5R): v -> o   [5R,6R): vT
// bf16 snapshots live in d_out (slot0/slot1) until the final GEMM.

typedef __attribute__((ext_vector_type(8))) short bf16x8;
typedef __attribute__((ext_vector_type(4))) float f32x4;
typedef unsigned short u16;
typedef unsigned int u32;

__device__ __forceinline__ u16 f2bf(float f) {
  union { float f; u32 u; } v; v.f = f;
  u32 r = v.u + 0x7fffu + ((v.u >> 16) & 1u);
  return (u16)(r >> 16);
}
__device__ __forceinline__ float bf2f(u16 b) {
  union { u32 u; float f; } v; v.u = ((u32)b) << 16;
  return v.f;
}
struct alignas(16) U16x8 { u16 v[8]; };

#define GLDS(gp, lp)                                                      \
  __builtin_amdgcn_global_load_lds(                                       \
      (const __attribute__((address_space(1))) void*)(gp),                \
      (__attribute__((address_space(3))) void*)(lp), 16, 0, 0)

// ---------------- conversion / transpose kernels ----------------

__global__ __launch_bounds__(256) void conv_f32_bf16(const float* __restrict__ in,
                                                     u16* __restrict__ out) {
  size_t i = ((size_t)blockIdx.x * 256 + threadIdx.x) * 8;
  float4 a = *(const float4*)(in + i);
  float4 b = *(const float4*)(in + i + 4);
  U16x8 w;
  w.v[0] = f2bf(a.x); w.v[1] = f2bf(a.y); w.v[2] = f2bf(a.z); w.v[3] = f2bf(a.w);
  w.v[4] = f2bf(b.x); w.v[5] = f2bf(b.y); w.v[6] = f2bf(b.z); w.v[7] = f2bf(b.w);
  *(U16x8*)(out + i) = w;
}

__global__ __launch_bounds__(256) void transpose_conv4(const float* __restrict__ W0,
                                                       const float* __restrict__ W1,
                                                       const float* __restrict__ W2,
                                                       const float* __restrict__ W3,
                                                       u16* __restrict__ out) {
  const int D = 2048;
  const float* in = (blockIdx.z == 0) ? W0 : (blockIdx.z == 1) ? W1
                  : (blockIdx.z == 2) ? W2 : W3;
  u16* o = out + (size_t)blockIdx.z * D * D;
  __shared__ float t[32][33];
  int bx = blockIdx.x * 32, by = blockIdx.y * 32;
  int tx = threadIdx.x & 31, ty = threadIdx.x >> 5;
#pragma unroll
  for (int i = 0; i < 32; i += 8)
    t[ty + i][tx] = in[(size_t)(by + ty + i) * D + bx + tx];
  __syncthreads();
#pragma unroll
  for (int i = 0; i < 32; i += 8)
    o[(size_t)(bx + ty + i) * D + by + tx] = f2bf(t[tx][ty + i]);
}

__global__ __launch_bounds__(256) void transpose_bf16(const u16* __restrict__ in,
                                                      u16* __restrict__ out) {
  const int D = 2048;
  size_t zoff = (size_t)blockIdx.z * D * D;
  in += zoff; out += zoff;
  __shared__ u16 t[32][34];
  int bx = blockIdx.x * 32, by = blockIdx.y * 32;
  int tx = threadIdx.x & 31, ty = threadIdx.x >> 5;
#pragma unroll
  for (int i = 0; i < 32; i += 8)
    t[ty + i][tx] = in[(size_t)(by + ty + i) * D + bx + tx];
  __syncthreads();
#pragma unroll
  for (int i = 0; i < 32; i += 8)
    out[(size_t)(bx + ty + i) * D + by + tx] = t[tx][ty + i];
}

// ============ 256^2 register-pipelined NT GEMM: C[M,N] = A[M,K] @ B[N,K]^T ============
// 512 threads, 8 waves (2M x 4N), per-wave output 128x64. Ring-4 of BK=32 K-tiles
// (4 x 32 KB = 128 KB LDS). Per K-tile tt:
//   lgkmcnt(12) [readers of reused slot serviced] ; vmcnt(4) [tile tt+1 landed] ;
//   barrier ; sched_barrier ; STG(tt+3) ; ds_read frags(tt+1) -> regsNext ;
//   32 MFMA on regsCur (setprio). One barrier per K-tile.
// LDS bank swizzle: 16B slot s at row r holds global slot s ^ ((r>>1)&3)
// (measured 0 bank conflicts in r4/r5). Requires K%64==0, K/32>=4, M,N mult of
// 256, grid.x % 8 == 0.
template <bool OUT_BF16>
__global__ __launch_bounds__(512, 2) void gemm256(
    const u16* __restrict__ A, int lda,
    const u16* __restrict__ B, int ldb,
    void* __restrict__ Cv, int ldc,
    int K, int nmat, int ntn, long long sBm, long long sCm) {
  extern __shared__ char smem[];
  u16* const As = (u16*)smem;             // [4][256*32] u16 (16 KB per slot)
  u16* const Bs = (u16*)(smem + 65536);

  // XCD-chunked decode: n fastest, then mat, then m
  u32 wg = blockIdx.x;
  u32 nchunk = gridDim.x >> 3;
  u32 swz = (wg & 7u) * nchunk + (wg >> 3);
  const int n0 = (int)(swz % (u32)ntn) * 256;
  u32 t2 = swz / (u32)ntn;
  const int mat = (int)(t2 % (u32)nmat);
  const int m0 = (int)(t2 / (u32)nmat) * 256;

  B += (size_t)mat * sBm;

  const int tid = threadIdx.x;
  const int lane = tid & 63, wave = tid >> 6;
  const int wm = (wave >> 2) * 128;       // 0 or 128
  const int wn = (wave & 3) * 64;         // 0,64,128,192
  const int fr = lane & 15, kgrp = lane >> 4;
  const u32 lo = (u32)(wave * 1024);      // wave-uniform LDS chunk for staging

  // staging map: thread covers LDS row srow (and srow+128), 16B slot (tid&3);
  // pre-swizzled global source slot so LDS stays linear (rule #21)
  const int srow = tid >> 2;
  const int ssl = (tid & 3) ^ ((srow >> 1) & 3);
  const u16* gA0 = A + (size_t)(m0 + srow) * lda + ssl * 8;
  const u16* gA1 = gA0 + (size_t)128 * lda;
  const u16* gB0 = B + (size_t)(n0 + srow) * ldb + ssl * 8;
  const u16* gB1 = gB0 + (size_t)128 * ldb;

  // ds_read swizzled k-offset (u16 units)
  const int koe = (kgrp ^ ((fr >> 1) & 3)) * 8;

#define STG(slot, kOff) do {                                              \
    char* la = (char*)As + (slot) * 16384 + lo;                           \
    char* lb = (char*)Bs + (slot) * 16384 + lo;                           \
    GLDS(gA0 + (kOff), la);                                               \
    GLDS(gA1 + (kOff), la + 8192);                                        \
    GLDS(gB0 + (kOff), lb);                                               \
    GLDS(gB1 + (kOff), lb + 8192);                                        \
  } while (0)

#define READF(FA, FB, sl) do {                                            \
    const u16* as_ = As + (sl) * 8192;                                    \
    const u16* bs_ = Bs + (sl) * 8192;                                    \
    _Pragma("unroll") for (int n_ = 0; n_ < 4; ++n_)                      \
      FB[n_] = *(const bf16x8*)&bs_[((wn + n_ * 16 + fr) << 5) + koe];    \
    _Pragma("unroll") for (int m_ = 0; m_ < 8; ++m_)                      \
      FA[m_] = *(const bf16x8*)&as_[((wm + m_ * 16 + fr) << 5) + koe];    \
  } while (0)

#define MMCL(FA, FB) do {                                                 \
    __builtin_amdgcn_s_setprio(1);                                        \
    _Pragma("unroll") for (int m_ = 0; m_ < 8; ++m_)                      \
    _Pragma("unroll") for (int n_ = 0; n_ < 4; ++n_)                      \
      acc[m_][n_] = __builtin_amdgcn_mfma_f32_16x16x32_bf16(              \
          FA[m_], FB[n_], acc[m_][n_], 0, 0, 0);                          \
    __builtin_amdgcn_s_setprio(0);                                        \
  } while (0)

// One K-tile: certify slot-reuse + tile(tt+1) landed, then overlap
// {STG(tt+3), ds_read(tt+1)} with 32 MFMA on regs read last iteration.
#define ITER(tt, CA, CB, NA, NB) do {                                     \
    if ((tt) + 3 < NT)                                                    \
      asm volatile("s_waitcnt lgkmcnt(12)" ::: "memory");                 \
    if ((tt) <= NT - 3)                                                   \
      asm volatile("s_waitcnt vmcnt(4)" ::: "memory");                    \
    else if ((tt) == NT - 2)                                              \
      asm volatile("s_waitcnt vmcnt(0)" ::: "memory");                    \
    if ((tt) <= NT - 2) {                                                 \
      __builtin_amdgcn_s_barrier();                                       \
      __builtin_amdgcn_sched_barrier(0);                                  \
    }                                                                     \
    if ((tt) + 3 < NT) STG(((tt) + 3) & 3, ((tt) + 3) * 32);              \
    if ((tt) + 1 < NT) READF(NA, NB, ((tt) + 1) & 3);                     \
    MMCL(CA, CB);                                                         \
  } while (0)

  f32x4 acc[8][4];
#pragma unroll
  for (int m = 0; m < 8; ++m)
#pragma unroll
    for (int n = 0; n < 4; ++n)
#pragma unroll
      for (int j = 0; j < 4; ++j) acc[m][n][j] = 0.f;

  const int NT = K >> 5;                  // even, >= 4
  bf16x8 fA0[8], fB0[4], fA1[8], fB1[4];

  // prologue: stage tiles 0,1,2; drain tile 0; read its frags
  STG(0, 0);
  STG(1, 32);
  STG(2, 64);
  asm volatile("s_waitcnt vmcnt(8)" ::: "memory");
  __builtin_amdgcn_s_barrier();
  __builtin_amdgcn_sched_barrier(0);
  READF(fA0, fB0, 0);

  for (int tt = 0; tt < NT; tt += 2) {
    ITER(tt, fA0, fB0, fA1, fB1);
    ITER(tt + 1, fA1, fB1, fA0, fB0);
  }
#undef ITER
#undef MMCL
#undef READF
#undef STG

  // epilogue: C/D layout col = lane&15, row = (lane>>4)*4 + j
  const int cl = lane & 15, rb = (lane >> 4) * 4;
  if (OUT_BF16) {
    u16* C = (u16*)Cv + (size_t)mat * sCm;
#pragma unroll
    for (int m = 0; m < 8; ++m)
#pragma unroll
      for (int n = 0; n < 4; ++n)
#pragma unroll
        for (int j = 0; j < 4; ++j)
          C[(size_t)(m0 + wm + m * 16 + rb + j) * ldc + (n0 + wn + n * 16 + cl)] =
              f2bf(acc[m][n][j]);
  } else {
    float* C = (float*)Cv + (size_t)mat * sCm;
#pragma unroll
    for (int m = 0; m < 8; ++m)
#pragma unroll
      for (int n = 0; n < 4; ++n)
#pragma unroll
        for (int j = 0; j < 4; ++j)
          C[(size_t)(m0 + wm + m * 16 + rb + j) * ldc + (n0 + wn + n * 16 + cl)] =
              acc[m][n][j];
  }
}

// ---------------- staging macro for 128^2 kernels (128x32 bf16 tile) ----------------
#define STAGE4(Abuf, Bbuf, kOff)                                                       \
  do {                                                                                 \
    GLDS(ga0 + (kOff), (char*)(Abuf) + lo);                                            \
    GLDS(ga1 + (kOff), (char*)(Abuf) + lo + 4096);                                     \
    GLDS(gb0 + (kOff), (char*)(Bbuf) + lo);                                            \
    GLDS(gb1 + (kOff), (char*)(Bbuf) + lo + 4096);                                     \
  } while (0)

// ---------------- 128^2 NT GEMM (m97 structure) for PV ----------------
// kmode: 0 plain, 2 causal PV (truncate K at m0+128).
template <bool OUT_BF16>
__global__ __launch_bounds__(256) void gemm_nt(
    const u16* __restrict__ A, long long sA, int lda,
    const u16* __restrict__ B, long long sB, int ldb,
    void* __restrict__ Cv, long long sC, int ldc,
    int K, int kmode) {
  const int n0 = blockIdx.x * 128, m0 = blockIdx.y * 128;
  const int z = blockIdx.z;
  const int kEnd = (kmode == 2) ? (m0 + 128) : K;

  A += (size_t)z * sA;
  B += (size_t)z * sB;

  __shared__ alignas(16) u16 As[2][128 * 32];
  __shared__ alignas(16) u16 Bs[2][128 * 32];

  const int tid = threadIdx.x;
  const int lane = tid & 63, wave = tid >> 6;
  const int wm = (wave >> 1) * 64, wn = (wave & 1) * 64;
  const int fr = lane & 15, kc = (lane >> 4) * 8;

  const u16* ga0 = A + (size_t)(m0 + (tid >> 2)) * lda + (tid & 3) * 8;
  const u16* ga1 = ga0 + (size_t)64 * lda;
  const u16* gb0 = B + (size_t)(n0 + (tid >> 2)) * ldb + (tid & 3) * 8;
  const u16* gb1 = gb0 + (size_t)64 * ldb;
  const u32 lo = (u32)(wave * 1024);

  f32x4 acc[4][4];
#pragma unroll
  for (int m = 0; m < 4; ++m)
#pragma unroll
    for (int n = 0; n < 4; ++n)
#pragma unroll
      for (int j = 0; j < 4; ++j) acc[m][n][j] = 0.f;

  const int nt = kEnd >> 5;
  STAGE4(&As[0][0], &Bs[0][0], 0);
  for (int t = 0; t < nt; ++t) {
    __syncthreads();
    if (t + 1 < nt) STAGE4(&As[(t + 1) & 1][0], &Bs[(t + 1) & 1][0], (t + 1) * 32);
    const u16* as = &As[t & 1][0];
    const u16* bs = &Bs[t & 1][0];
    bf16x8 af[4], bfr[4];
#pragma unroll
    for (int m = 0; m < 4; ++m)
      af[m] = *(const bf16x8*)&as[(wm + m * 16 + fr) * 32 + kc];
#pragma unroll
    for (int n = 0; n < 4; ++n)
      bfr[n] = *(const bf16x8*)&bs[(wn + n * 16 + fr) * 32 + kc];
#pragma unroll
    for (int m = 0; m < 4; ++m)
#pragma unroll
      for (int n = 0; n < 4; ++n)
        acc[m][n] = __builtin_amdgcn_mfma_f32_16x16x32_bf16(af[m], bfr[n],
                                                            acc[m][n], 0, 0, 0);
  }

  const int col = lane & 15, rb = (lane >> 4) * 4;
  if (OUT_BF16) {
    u16* C = (u16*)Cv + (size_t)z * sC;
#pragma unroll
    for (int m = 0; m < 4; ++m)
#pragma unroll
      for (int n = 0; n < 4; ++n)
#pragma unroll
        for (int j = 0; j < 4; ++j)
          C[(size_t)(m0 + wm + m * 16 + rb + j) * ldc + (n0 + wn + n * 16 + col)] =
              f2bf(acc[m][n][j]);
  } else {
    float* C = (float*)Cv + (size_t)z * sC;
#pragma unroll
    for (int m = 0; m < 4; ++m)
#pragma unroll
      for (int n = 0; n < 4; ++n)
#pragma unroll
        for (int j = 0; j < 4; ++j)
          C[(size_t)(m0 + wm + m * 16 + rb + j) * ldc + (n0 + wn + n * 16 + col)] =
              acc[m][n][j];
  }
}

// ---------------- snapshot QK sweep (K=1024 per pass, 128^2 tiles) ----------------
__global__ __launch_bounds__(256) void qk_mega(
    const u16* __restrict__ A, const u16* __restrict__ B,
    u16* __restrict__ snapA, u16* __restrict__ snapB,
    float scaleA, float scaleB,
    const u16* __restrict__ initSrc, float initScale) {
  const int lda = 2048;
  const int m0 = blockIdx.y * 128, n0 = blockIdx.x * 128;
  if (n0 >= m0 + 128) return;  // fully masked tile
  const size_t zWE = (size_t)blockIdx.z * 4194304ull;

  __shared__ alignas(16) u16 As[2][128 * 32];
  __shared__ alignas(16) u16 Bs[2][128 * 32];

  const int tid = threadIdx.x;
  const int lane = tid & 63, wave = tid >> 6;
  const int wm = (wave >> 1) * 64, wn = (wave & 1) * 64;
  const int fr = lane & 15, kc = (lane >> 4) * 8;
  const int col = lane & 15, rb = (lane >> 4) * 4;

  const u16* ga0 = A + zWE + (size_t)(m0 + (tid >> 2)) * lda + (tid & 3) * 8;
  const u16* ga1 = ga0 + (size_t)64 * lda;
  const u16* gb0 = B + zWE + (size_t)(n0 + (tid >> 2)) * lda + (tid & 3) * 8;
  const u16* gb1 = gb0 + (size_t)64 * lda;
  const u32 lo = (u32)(wave * 1024);

  f32x4 acc[4][4];
  if (initSrc) {
    const u16* ip = initSrc + zWE;
#pragma unroll
    for (int m = 0; m < 4; ++m)
#pragma unroll
      for (int n = 0; n < 4; ++n)
#pragma unroll
        for (int j = 0; j < 4; ++j)
          acc[m][n][j] = bf2f(ip[(size_t)(m0 + wm + m * 16 + rb + j) * 2048 +
                                 (n0 + wn + n * 16 + col)]) * initScale;
  } else {
#pragma unroll
    for (int m = 0; m < 4; ++m)
#pragma unroll
      for (int n = 0; n < 4; ++n)
#pragma unroll
        for (int j = 0; j < 4; ++j) acc[m][n][j] = 0.f;
  }

#define SNAPW(ptr, scl)                                                                \
  do {                                                                                 \
    u16* sp = (ptr) + zWE;                                                             \
    _Pragma("unroll") for (int m = 0; m < 4; ++m)                                      \
    _Pragma("unroll") for (int n = 0; n < 4; ++n)                                      \
    _Pragma("unroll") for (int j = 0; j < 4; ++j)                                      \
        sp[(size_t)(m0 + wm + m * 16 + rb + j) * 2048 + (n0 + wn + n * 16 + col)] =    \
            f2bf(acc[m][n][j] * (scl));                                                \
  } while (0)

  STAGE4(&As[0][0], &Bs[0][0], 0);
  for (int t = 0; t < 32; ++t) {
    __syncthreads();
    if (t + 1 < 32) STAGE4(&As[(t + 1) & 1][0], &Bs[(t + 1) & 1][0], (t + 1) * 32);
    const u16* as = &As[t & 1][0];
    const u16* bs = &Bs[t & 1][0];
    bf16x8 af[4], bfr[4];
#pragma unroll
    for (int m = 0; m < 4; ++m)
      af[m] = *(const bf16x8*)&as[(wm + m * 16 + fr) * 32 + kc];
#pragma unroll
    for (int n = 0; n < 4; ++n)
      bfr[n] = *(const bf16x8*)&bs[(wn + n * 16 + fr) * 32 + kc];
#pragma unroll
    for (int m = 0; m < 4; ++m)
#pragma unroll
      for (int n = 0; n < 4; ++n)
        acc[m][n] = __builtin_amdgcn_mfma_f32_16x16x32_bf16(af[m], bfr[n],
                                                            acc[m][n], 0, 0, 0);
    if (t == 15) SNAPW(snapA, scaleA);  // K=512 prefix done
  }
  SNAPW(snapB, scaleB);
#undef SNAPW
}

// ---------------- causal row softmax on scaled bf16 logits ----------------
// Writes only cols [0, roundup128(r+1)) — PV never reads beyond its kEnd.
__global__ __launch_bounds__(256) void softmax_causal(const u16* __restrict__ in,
                                                      u16* __restrict__ out) {
  const int S = 2048;
  const size_t WEz = (size_t)S * S * blockIdx.y;
  const int r = blockIdx.x;
  const int tid = threadIdx.x;
  const int lane = tid & 63, wave = tid >> 6;
  const int c0 = tid * 8;
  const int nvalid = r + 1;
  const int nwrite = (r & ~127) + 128;
  const u16* rowp = in + WEz + (size_t)r * S;

  float x[8];
  if (c0 < nvalid) {
    U16x8 a = *(const U16x8*)(rowp + c0);
#pragma unroll
    for (int i = 0; i < 8; ++i) x[i] = bf2f(a.v[i]);
  } else {
#pragma unroll
    for (int i = 0; i < 8; ++i) x[i] = 0.f;
  }

  float mx = -3e38f;
#pragma unroll
  for (int i = 0; i < 8; ++i)
    if (c0 + i < nvalid) mx = fmaxf(mx, x[i]);
#pragma unroll
  for (int off = 32; off > 0; off >>= 1) mx = fmaxf(mx, __shfl_xor(mx, off));
  __shared__ float redm[4], reds[4];
  if (lane == 0) redm[wave] = mx;
  __syncthreads();
  mx = fmaxf(fmaxf(redm[0], redm[1]), fmaxf(redm[2], redm[3]));

  float e[8], sum = 0.f;
#pragma unroll
  for (int i = 0; i < 8; ++i) {
    e[i] = (c0 + i < nvalid) ? __expf(x[i] - mx) : 0.f;
    sum += e[i];
  }
#pragma unroll
  for (int off = 32; off > 0; off >>= 1) sum += __shfl_xor(sum, off);
  if (lane == 0) reds[wave] = sum;
  __syncthreads();
  sum = reds[0] + reds[1] + reds[2] + reds[3];
  float inv = 1.f / sum;

  if (c0 < nwrite) {
    U16x8 w;
#pragma unroll
    for (int i = 0; i < 8; ++i) w.v[i] = f2bf(e[i] * inv);
    *(U16x8*)(out + WEz + (size_t)r * S + c0) = w;
  }
}

// ---------------- launcher ----------------
extern "C" void kernel_launch(void* const* d_in, const int* in_sizes, int n_in,
                              void* d_out, int out_size, void* d_ws, size_t ws_size,
                              hipStream_t stream) {
  (void)in_sizes; (void)n_in; (void)out_size; (void)ws_size;
  const float* x  = (const float*)d_in[0];
  // d_in[1] is the boolean causal mask; causality is hard-coded.
  const float* Wq = (const float*)d_in[2];
  const float* Wk = (const float*)d_in[3];
  const float* Wv = (const float*)d_in[4];
  const float* Wo = (const float*)d_in[5];
  float* out = (float*)d_out;

  char* w = (char*)d_ws;
  const size_t R  = 33554432ull;
  const long long WE = 4194304LL;   // 2048*2048 elems

  u16* xb  = (u16*)(w);
  u16* wT  = (u16*)(w + R);
  u16* wqT = wT;
  u16* woT = wT + 3 * WE;
  u16* q   = (u16*)(w + 2 * R);
  u16* kk  = (u16*)(w + 3 * R);
  u16* v   = (u16*)(w + 4 * R);
  u16* vT  = (u16*)(w + 5 * R);
  u16* o   = v;                      // v dead after transpose
  u16* attnx = xb;                   // xb dead after projections
  u16* slot0 = (u16*)d_out;          // 16.8M elems (4 batches x S x S bf16)
  u16* slot1 = slot0 + 16777216ull;  // second half of d_out

  const float sc0 = 1.0f / sqrtf(512.0f);
  const float sc1 = 1.0f / sqrtf(1024.0f);
  const float sc2 = 1.0f / sqrtf(1536.0f);
  const float sc3 = 1.0f / sqrtf(2048.0f);

  // allow 128 KB dynamic LDS on the big-tile GEMM (deterministic, capture-safe)
  hipFuncSetAttribute(reinterpret_cast<const void*>(&gemm256<true>),
                      hipFuncAttributeMaxDynamicSharedMemorySize, 131072);
  hipFuncSetAttribute(reinterpret_cast<const void*>(&gemm256<false>),
                      hipFuncAttributeMaxDynamicSharedMemorySize, 131072);

  // 1) x -> bf16; weights -> transposed bf16
  conv_f32_bf16<<<8192, 256, 0, stream>>>(x, xb);
  transpose_conv4<<<dim3(64, 64, 4), 256, 0, stream>>>(Wq, Wk, Wv, Wo, wT);
  // 2) fused q,k,v projection: M=8192, per-mat N=2048, K=2048, 3 mats
  gemm256<true><<<dim3(768), 512, 131072, stream>>>(
      xb, 2048, wqT, 2048, q, 2048, 2048, 3, 8, WE, 16777216LL);
  // 3) v -> vT
  transpose_bf16<<<dim3(64, 64, 4), 256, 0, stream>>>(v, vT);
  // 4) pass A: K=0..1024, snapshots -> slot0 (slice0), slot1 (slice1)
  qk_mega<<<dim3(16, 16, 4), 256, 0, stream>>>(q, kk, slot0, slot1, sc0, sc1,
                                               nullptr, 0.f);
  softmax_causal<<<dim3(2048, 4), 256, 0, stream>>>(slot0, slot0);
  gemm_nt<true><<<dim3(4, 16, 4), 256, 0, stream>>>(
      slot0, WE, 2048, vT, WE, 2048, o, WE, 2048, 2048, 2);
  softmax_causal<<<dim3(2048, 4), 256, 0, stream>>>(slot1, attnx);
  gemm_nt<true><<<dim3(4, 16, 4), 256, 0, stream>>>(
      attnx, WE, 2048, vT + 1048576, WE, 2048, o + 512, WE, 2048, 2048, 2);
  // 5) pass B: K=1024..2048, init from slot1 (* sqrt(1024)), snapshots slices 2,3
  qk_mega<<<dim3(16, 16, 4), 256, 0, stream>>>(q + 1024, kk + 1024, slot0, slot1,
                                               sc2, sc3, slot1, 32.0f);
  softmax_causal<<<dim3(2048, 4), 256, 0, stream>>>(slot0, slot0);
  gemm_nt<true><<<dim3(4, 16, 4), 256, 0, stream>>>(
      slot0, WE, 2048, vT + 2 * 1048576, WE, 2048, o + 1024, WE, 2048, 2048, 2);
  softmax_causal<<<dim3(2048, 4), 256, 0, stream>>>(slot1, slot1);
  gemm_nt<true><<<dim3(4, 16, 4), 256, 0, stream>>>(
      slot1, WE, 2048, vT + 3 * 1048576, WE, 2048, o + 1536, WE, 2048, 2048, 2);
  // 6) out = o @ Wo: M=8192, N=2048, K=2048
  gemm256<false><<<dim3(256), 512, 131072, stream>>>(
      o, 2048, woT, 2048, out, 2048, 2048, 1, 8, 0LL, 0LL);
}

// Round 7
// 639.573 us; speedup vs baseline: 1.0211x; 1.0063x over previous
//
#include <hip/hip_runtime.h>

// MMHSA Matryoshka attention, B=4, S=2048, D=2048, slices {512,1024,1536,2048}.
// Big GEMMs (QKV proj, final proj): 256^2-tile bf16 MFMA kernel, ring-4 BK=32
//   LDS slots, register-pipelined frags, one barrier per K-tile, counted
//   vmcnt/lgkmcnt, setprio, XOR bank-swizzle (0 conflicts measured).
//   R7: tile decode gives each XCD ONE n-tile (B-panels 3MB -> L2-resident),
//   mat-fastest then m within XCD (A m-panel shared by 3 adjacent blocks).
// Attention: 2-pass snapshot QK sweep + bf16 softmax (write-truncated) + 128^2 PV.
//
// Workspace (R = 32 MiB, 6R = 201.3 MB):
//   [0,R):    xb (bf16 x)          -> attn scratch for slice 1
//   [R,2R):   wqT wkT wvT woT bf16
//   [2R,3R):  q   [3R,4R): k   [4R,5R): v -> o   [5R,6R): vT
// bf16 snapshots live in d_out (slot0/slot1) until the final GEMM.

typedef __attribute__((ext_vector_type(8))) short bf16x8;
typedef __attribute__((ext_vector_type(4))) float f32x4;
typedef unsigned short u16;
typedef unsigned int u32;

__device__ __forceinline__ u16 f2bf(float f) {
  union { float f; u32 u; } v; v.f = f;
  u32 r = v.u + 0x7fffu + ((v.u >> 16) & 1u);
  return (u16)(r >> 16);
}
__device__ __forceinline__ float bf2f(u16 b) {
  union { u32 u; float f; } v; v.u = ((u32)b) << 16;
  return v.f;
}
struct alignas(16) U16x8 { u16 v[8]; };

#define GLDS(gp, lp)                                                      \
  __builtin_amdgcn_global_load_lds(                                       \
      (const __attribute__((address_space(1))) void*)(gp),                \
      (__attribute__((address_space(3))) void*)(lp), 16, 0, 0)

// ---------------- conversion / transpose kernels ----------------

__global__ __launch_bounds__(256) void conv_f32_bf16(const float* __restrict__ in,
                                                     u16* __restrict__ out) {
  size_t i = ((size_t)blockIdx.x * 256 + threadIdx.x) * 8;
  float4 a = *(const float4*)(in + i);
  float4 b = *(const float4*)(in + i + 4);
  U16x8 w;
  w.v[0] = f2bf(a.x); w.v[1] = f2bf(a.y); w.v[2] = f2bf(a.z); w.v[3] = f2bf(a.w);
  w.v[4] = f2bf(b.x); w.v[5] = f2bf(b.y); w.v[6] = f2bf(b.z); w.v[7] = f2bf(b.w);
  *(U16x8*)(out + i) = w;
}

__global__ __launch_bounds__(256) void transpose_conv4(const float* __restrict__ W0,
                                                       const float* __restrict__ W1,
                                                       const float* __restrict__ W2,
                                                       const float* __restrict__ W3,
                                                       u16* __restrict__ out) {
  const int D = 2048;
  const float* in = (blockIdx.z == 0) ? W0 : (blockIdx.z == 1) ? W1
                  : (blockIdx.z == 2) ? W2 : W3;
  u16* o = out + (size_t)blockIdx.z * D * D;
  __shared__ float t[32][33];
  int bx = blockIdx.x * 32, by = blockIdx.y * 32;
  int tx = threadIdx.x & 31, ty = threadIdx.x >> 5;
#pragma unroll
  for (int i = 0; i < 32; i += 8)
    t[ty + i][tx] = in[(size_t)(by + ty + i) * D + bx + tx];
  __syncthreads();
#pragma unroll
  for (int i = 0; i < 32; i += 8)
    o[(size_t)(bx + ty + i) * D + by + tx] = f2bf(t[tx][ty + i]);
}

__global__ __launch_bounds__(256) void transpose_bf16(const u16* __restrict__ in,
                                                      u16* __restrict__ out) {
  const int D = 2048;
  size_t zoff = (size_t)blockIdx.z * D * D;
  in += zoff; out += zoff;
  __shared__ u16 t[32][34];
  int bx = blockIdx.x * 32, by = blockIdx.y * 32;
  int tx = threadIdx.x & 31, ty = threadIdx.x >> 5;
#pragma unroll
  for (int i = 0; i < 32; i += 8)
    t[ty + i][tx] = in[(size_t)(by + ty + i) * D + bx + tx];
  __syncthreads();
#pragma unroll
  for (int i = 0; i < 32; i += 8)
    out[(size_t)(bx + ty + i) * D + by + tx] = t[tx][ty + i];
}

// ============ 256^2 register-pipelined NT GEMM: C[M,N] = A[M,K] @ B[N,K]^T ============
// 512 threads, 8 waves (2M x 4N), per-wave output 128x64. Ring-4 of BK=32 K-tiles
// (4 x 32 KB = 128 KB LDS). Per K-tile tt:
//   lgkmcnt(12) ; vmcnt(4) ; barrier ; sched_barrier ; STG(tt+3) ;
//   ds_read frags(tt+1) ; 32 MFMA on regs read last iter (setprio).
// Decode (R7): XCD x owns n-tile x (requires ntn == 8, grid.x % 8 == 0);
//   within XCD: mat fastest, then m -> B-panels (nmat MB) L2-resident, A m-panel
//   shared by nmat adjacent blocks, streamed once per XCD.
// Requires K%64==0, K/32>=4, M mult of 256, N == 2048 (8 n-tiles).
template <bool OUT_BF16>
__global__ __launch_bounds__(512, 2) void gemm256(
    const u16* __restrict__ A, int lda,
    const u16* __restrict__ B, int ldb,
    void* __restrict__ Cv, int ldc,
    int K, int nmat, long long sBm, long long sCm) {
  extern __shared__ char smem[];
  u16* const As = (u16*)smem;             // [4][256*32] u16 (16 KB per slot)
  u16* const Bs = (u16*)(smem + 65536);

  // XCD-residency decode: n-tile = XCD id; chunk = mat (fastest) x m-panel
  const u32 wg = blockIdx.x;
  const int n0 = (int)(wg & 7u) * 256;
  const u32 c = wg >> 3;
  const int mat = (int)(c % (u32)nmat);
  const int m0 = (int)(c / (u32)nmat) * 256;

  B += (size_t)mat * sBm;

  const int tid = threadIdx.x;
  const int lane = tid & 63, wave = tid >> 6;
  const int wm = (wave >> 2) * 128;       // 0 or 128
  const int wn = (wave & 3) * 64;         // 0,64,128,192
  const int fr = lane & 15, kgrp = lane >> 4;
  const u32 lo = (u32)(wave * 1024);      // wave-uniform LDS chunk for staging

  // staging map: thread covers LDS row srow (and srow+128), 16B slot (tid&3);
  // pre-swizzled global source slot so LDS stays linear (rule #21)
  const int srow = tid >> 2;
  const int ssl = (tid & 3) ^ ((srow >> 1) & 3);
  const u16* gA0 = A + (size_t)(m0 + srow) * lda + ssl * 8;
  const u16* gA1 = gA0 + (size_t)128 * lda;
  const u16* gB0 = B + (size_t)(n0 + srow) * ldb + ssl * 8;
  const u16* gB1 = gB0 + (size_t)128 * ldb;

  // ds_read swizzled k-offset (u16 units)
  const int koe = (kgrp ^ ((fr >> 1) & 3)) * 8;

#define STG(slot, kOff) do {                                              \
    char* la = (char*)As + (slot) * 16384 + lo;                           \
    char* lb = (char*)Bs + (slot) * 16384 + lo;                           \
    GLDS(gA0 + (kOff), la);                                               \
    GLDS(gA1 + (kOff), la + 8192);                                       \
    GLDS(gB0 + (kOff), lb);                                               \
    GLDS(gB1 + (kOff), lb + 8192);                                       \
  } while (0)

#define READF(FA, FB, sl) do {                                            \
    const u16* as_ = As + (sl) * 8192;                                    \
    const u16* bs_ = Bs + (sl) * 8192;                                    \
    _Pragma("unroll") for (int n_ = 0; n_ < 4; ++n_)                      \
      FB[n_] = *(const bf16x8*)&bs_[((wn + n_ * 16 + fr) << 5) + koe];    \
    _Pragma("unroll") for (int m_ = 0; m_ < 8; ++m_)                      \
      FA[m_] = *(const bf16x8*)&as_[((wm + m_ * 16 + fr) << 5) + koe];    \
  } while (0)

#define MMCL(FA, FB) do {                                                 \
    __builtin_amdgcn_s_setprio(1);                                        \
    _Pragma("unroll") for (int m_ = 0; m_ < 8; ++m_)                      \
    _Pragma("unroll") for (int n_ = 0; n_ < 4; ++n_)                      \
      acc[m_][n_] = __builtin_amdgcn_mfma_f32_16x16x32_bf16(              \
          FA[m_], FB[n_], acc[m_][n_], 0, 0, 0);                          \
    __builtin_amdgcn_s_setprio(0);                                        \
  } while (0)

#define ITER(tt, CA, CB, NA, NB) do {                                     \
    if ((tt) + 3 < NT)                                                    \
      asm volatile("s_waitcnt lgkmcnt(12)" ::: "memory");                 \
    if ((tt) <= NT - 3)                                                   \
      asm volatile("s_waitcnt vmcnt(4)" ::: "memory");                    \
    else if ((tt) == NT - 2)                                              \
      asm volatile("s_waitcnt vmcnt(0)" ::: "memory");                    \
    if ((tt) <= NT - 2) {                                                 \
      __builtin_amdgcn_s_barrier();                                       \
      __builtin_amdgcn_sched_barrier(0);                                  \
    }                                                                     \
    if ((tt) + 3 < NT) STG(((tt) + 3) & 3, ((tt) + 3) * 32);              \
    if ((tt) + 1 < NT) READF(NA, NB, ((tt) + 1) & 3);                     \
    MMCL(CA, CB);                                                         \
  } while (0)

  f32x4 acc[8][4];
#pragma unroll
  for (int m = 0; m < 8; ++m)
#pragma unroll
    for (int n = 0; n < 4; ++n)
#pragma unroll
      for (int j = 0; j < 4; ++j) acc[m][n][j] = 0.f;

  const int NT = K >> 5;                  // even, >= 4
  bf16x8 fA0[8], fB0[4], fA1[8], fB1[4];

  // prologue: stage tiles 0,1,2; drain tile 0; read its frags
  STG(0, 0);
  STG(1, 32);
  STG(2, 64);
  asm volatile("s_waitcnt vmcnt(8)" ::: "memory");
  __builtin_amdgcn_s_barrier();
  __builtin_amdgcn_sched_barrier(0);
  READF(fA0, fB0, 0);

  for (int tt = 0; tt < NT; tt += 2) {
    ITER(tt, fA0, fB0, fA1, fB1);
    ITER(tt + 1, fA1, fB1, fA0, fB0);
  }
#undef ITER
#undef MMCL
#undef READF
#undef STG

  // epilogue: C/D layout col = lane&15, row = (lane>>4)*4 + j
  const int cl = lane & 15, rb = (lane >> 4) * 4;
  if (OUT_BF16) {
    u16* C = (u16*)Cv + (size_t)mat * sCm;
#pragma unroll
    for (int m = 0; m < 8; ++m)
#pragma unroll
      for (int n = 0; n < 4; ++n)
#pragma unroll
        for (int j = 0; j < 4; ++j)
          C[(size_t)(m0 + wm + m * 16 + rb + j) * ldc + (n0 + wn + n * 16 + cl)] =
              f2bf(acc[m][n][j]);
  } else {
    float* C = (float*)Cv + (size_t)mat * sCm;
#pragma unroll
    for (int m = 0; m < 8; ++m)
#pragma unroll
      for (int n = 0; n < 4; ++n)
#pragma unroll
        for (int j = 0; j < 4; ++j)
          C[(size_t)(m0 + wm + m * 16 + rb + j) * ldc + (n0 + wn + n * 16 + cl)] =
              acc[m][n][j];
  }
}

// ---------------- staging macro for 128^2 kernels (128x32 bf16 tile) ----------------
#define STAGE4(Abuf, Bbuf, kOff)                                                       \
  do {                                                                                 \
    GLDS(ga0 + (kOff), (char*)(Abuf) + lo);                                            \
    GLDS(ga1 + (kOff), (char*)(Abuf) + lo + 4096);                                     \
    GLDS(gb0 + (kOff), (char*)(Bbuf) + lo);                                            \
    GLDS(gb1 + (kOff), (char*)(Bbuf) + lo + 4096);                                     \
  } while (0)

// ---------------- 128^2 NT GEMM (m97 structure) for PV ----------------
// kmode: 0 plain, 2 causal PV (truncate K at m0+128).
template <bool OUT_BF16>
__global__ __launch_bounds__(256) void gemm_nt(
    const u16* __restrict__ A, long long sA, int lda,
    const u16* __restrict__ B, long long sB, int ldb,
    void* __restrict__ Cv, long long sC, int ldc,
    int K, int kmode) {
  const int n0 = blockIdx.x * 128, m0 = blockIdx.y * 128;
  const int z = blockIdx.z;
  const int kEnd = (kmode == 2) ? (m0 + 128) : K;

  A += (size_t)z * sA;
  B += (size_t)z * sB;

  __shared__ alignas(16) u16 As[2][128 * 32];
  __shared__ alignas(16) u16 Bs[2][128 * 32];

  const int tid = threadIdx.x;
  const int lane = tid & 63, wave = tid >> 6;
  const int wm = (wave >> 1) * 64, wn = (wave & 1) * 64;
  const int fr = lane & 15, kc = (lane >> 4) * 8;

  const u16* ga0 = A + (size_t)(m0 + (tid >> 2)) * lda + (tid & 3) * 8;
  const u16* ga1 = ga0 + (size_t)64 * lda;
  const u16* gb0 = B + (size_t)(n0 + (tid >> 2)) * ldb + (tid & 3) * 8;
  const u16* gb1 = gb0 + (size_t)64 * ldb;
  const u32 lo = (u32)(wave * 1024);

  f32x4 acc[4][4];
#pragma unroll
  for (int m = 0; m < 4; ++m)
#pragma unroll
    for (int n = 0; n < 4; ++n)
#pragma unroll
      for (int j = 0; j < 4; ++j) acc[m][n][j] = 0.f;

  const int nt = kEnd >> 5;
  STAGE4(&As[0][0], &Bs[0][0], 0);
  for (int t = 0; t < nt; ++t) {
    __syncthreads();
    if (t + 1 < nt) STAGE4(&As[(t + 1) & 1][0], &Bs[(t + 1) & 1][0], (t + 1) * 32);
    const u16* as = &As[t & 1][0];
    const u16* bs = &Bs[t & 1][0];
    bf16x8 af[4], bfr[4];
#pragma unroll
    for (int m = 0; m < 4; ++m)
      af[m] = *(const bf16x8*)&as[(wm + m * 16 + fr) * 32 + kc];
#pragma unroll
    for (int n = 0; n < 4; ++n)
      bfr[n] = *(const bf16x8*)&bs[(wn + n * 16 + fr) * 32 + kc];
#pragma unroll
    for (int m = 0; m < 4; ++m)
#pragma unroll
      for (int n = 0; n < 4; ++n)
        acc[m][n] = __builtin_amdgcn_mfma_f32_16x16x32_bf16(af[m], bfr[n],
                                                            acc[m][n], 0, 0, 0);
  }

  const int col = lane & 15, rb = (lane >> 4) * 4;
  if (OUT_BF16) {
    u16* C = (u16*)Cv + (size_t)z * sC;
#pragma unroll
    for (int m = 0; m < 4; ++m)
#pragma unroll
      for (int n = 0; n < 4; ++n)
#pragma unroll
        for (int j = 0; j < 4; ++j)
          C[(size_t)(m0 + wm + m * 16 + rb + j) * ldc + (n0 + wn + n * 16 + col)] =
              f2bf(acc[m][n][j]);
  } else {
    float* C = (float*)Cv + (size_t)z * sC;
#pragma unroll
    for (int m = 0; m < 4; ++m)
#pragma unroll
      for (int n = 0; n < 4; ++n)
#pragma unroll
        for (int j = 0; j < 4; ++j)
          C[(size_t)(m0 + wm + m * 16 + rb + j) * ldc + (n0 + wn + n * 16 + col)] =
              acc[m][n][j];
  }
}

// ---------------- snapshot QK sweep (K=1024 per pass, 128^2 tiles) ----------------
__global__ __launch_bounds__(256) void qk_mega(
    const u16* __restrict__ A, const u16* __restrict__ B,
    u16* __restrict__ snapA, u16* __restrict__ snapB,
    float scaleA, float scaleB,
    const u16* __restrict__ initSrc, float initScale) {
  const int lda = 2048;
  const int m0 = blockIdx.y * 128, n0 = blockIdx.x * 128;
  if (n0 >= m0 + 128) return;  // fully masked tile
  const size_t zWE = (size_t)blockIdx.z * 4194304ull;

  __shared__ alignas(16) u16 As[2][128 * 32];
  __shared__ alignas(16) u16 Bs[2][128 * 32];

  const int tid = threadIdx.x;
  const int lane = tid & 63, wave = tid >> 6;
  const int wm = (wave >> 1) * 64, wn = (wave & 1) * 64;
  const int fr = lane & 15, kc = (lane >> 4) * 8;
  const int col = lane & 15, rb = (lane >> 4) * 4;

  const u16* ga0 = A + zWE + (size_t)(m0 + (tid >> 2)) * lda + (tid & 3) * 8;
  const u16* ga1 = ga0 + (size_t)64 * lda;
  const u16* gb0 = B + zWE + (size_t)(n0 + (tid >> 2)) * lda + (tid & 3) * 8;
  const u16* gb1 = gb0 + (size_t)64 * lda;
  const u32 lo = (u32)(wave * 1024);

  f32x4 acc[4][4];
  if (initSrc) {
    const u16* ip = initSrc + zWE;
#pragma unroll
    for (int m = 0; m < 4; ++m)
#pragma unroll
      for (int n = 0; n < 4; ++n)
#pragma unroll
        for (int j = 0; j < 4; ++j)
          acc[m][n][j] = bf2f(ip[(size_t)(m0 + wm + m * 16 + rb + j) * 2048 +
                                 (n0 + wn + n * 16 + col)]) * initScale;
  } else {
#pragma unroll
    for (int m = 0; m < 4; ++m)
#pragma unroll
      for (int n = 0; n < 4; ++n)
#pragma unroll
        for (int j = 0; j < 4; ++j) acc[m][n][j] = 0.f;
  }

#define SNAPW(ptr, scl)                                                                \
  do {                                                                                 \
    u16* sp = (ptr) + zWE;                                                             \
    _Pragma("unroll") for (int m = 0; m < 4; ++m)                                      \
    _Pragma("unroll") for (int n = 0; n < 4; ++n)                                      \
    _Pragma("unroll") for (int j = 0; j < 4; ++j)                                      \
        sp[(size_t)(m0 + wm + m * 16 + rb + j) * 2048 + (n0 + wn + n * 16 + col)] =    \
            f2bf(acc[m][n][j] * (scl));                                                \
  } while (0)

  STAGE4(&As[0][0], &Bs[0][0], 0);
  for (int t = 0; t < 32; ++t) {
    __syncthreads();
    if (t + 1 < 32) STAGE4(&As[(t + 1) & 1][0], &Bs[(t + 1) & 1][0], (t + 1) * 32);
    const u16* as = &As[t & 1][0];
    const u16* bs = &Bs[t & 1][0];
    bf16x8 af[4], bfr[4];
#pragma unroll
    for (int m = 0; m < 4; ++m)
      af[m] = *(const bf16x8*)&as[(wm + m * 16 + fr) * 32 + kc];
#pragma unroll
    for (int n = 0; n < 4; ++n)
      bfr[n] = *(const bf16x8*)&bs[(wn + n * 16 + fr) * 32 + kc];
#pragma unroll
    for (int m = 0; m < 4; ++m)
#pragma unroll
      for (int n = 0; n < 4; ++n)
        acc[m][n] = __builtin_amdgcn_mfma_f32_16x16x32_bf16(af[m], bfr[n],
                                                            acc[m][n], 0, 0, 0);
    if (t == 15) SNAPW(snapA, scaleA);  // K=512 prefix done
  }
  SNAPW(snapB, scaleB);
#undef SNAPW
}

// ---------------- causal row softmax on scaled bf16 logits ----------------
// Writes only cols [0, roundup128(r+1)) — PV never reads beyond its kEnd.
__global__ __launch_bounds__(256) void softmax_causal(const u16* __restrict__ in,
                                                      u16* __restrict__ out) {
  const int S = 2048;
  const size_t WEz = (size_t)S * S * blockIdx.y;
  const int r = blockIdx.x;
  const int tid = threadIdx.x;
  const int lane = tid & 63, wave = tid >> 6;
  const int c0 = tid * 8;
  const int nvalid = r + 1;
  const int nwrite = (r & ~127) + 128;
  const u16* rowp = in + WEz + (size_t)r * S;

  float x[8];
  if (c0 < nvalid) {
    U16x8 a = *(const U16x8*)(rowp + c0);
#pragma unroll
    for (int i = 0; i < 8; ++i) x[i] = bf2f(a.v[i]);
  } else {
#pragma unroll
    for (int i = 0; i < 8; ++i) x[i] = 0.f;
  }

  float mx = -3e38f;
#pragma unroll
  for (int i = 0; i < 8; ++i)
    if (c0 + i < nvalid) mx = fmaxf(mx, x[i]);
#pragma unroll
  for (int off = 32; off > 0; off >>= 1) mx = fmaxf(mx, __shfl_xor(mx, off));
  __shared__ float redm[4], reds[4];
  if (lane == 0) redm[wave] = mx;
  __syncthreads();
  mx = fmaxf(fmaxf(redm[0], redm[1]), fmaxf(redm[2], redm[3]));

  float e[8], sum = 0.f;
#pragma unroll
  for (int i = 0; i < 8; ++i) {
    e[i] = (c0 + i < nvalid) ? __expf(x[i] - mx) : 0.f;
    sum += e[i];
  }
#pragma unroll
  for (int off = 32; off > 0; off >>= 1) sum += __shfl_xor(sum, off);
  if (lane == 0) reds[wave] = sum;
  __syncthreads();
  sum = reds[0] + reds[1] + reds[2] + reds[3];
  float inv = 1.f / sum;

  if (c0 < nwrite) {
    U16x8 w;
#pragma unroll
    for (int i = 0; i < 8; ++i) w.v[i] = f2bf(e[i] * inv);
    *(U16x8*)(out + WEz + (size_t)r * S + c0) = w;
  }
}

// ---------------- launcher ----------------
extern "C" void kernel_launch(void* const* d_in, const int* in_sizes, int n_in,
                              void* d_out, int out_size, void* d_ws, size_t ws_size,
                              hipStream_t stream) {
  (void)in_sizes; (void)n_in; (void)out_size; (void)ws_size;
  const float* x  = (const float*)d_in[0];
  // d_in[1] is the boolean causal mask; causality is hard-coded.
  const float* Wq = (const float*)d_in[2];
  const float* Wk = (const float*)d_in[3];
  const float* Wv = (const float*)d_in[4];
  const float* Wo = (const float*)d_in[5];
  float* out = (float*)d_out;

  char* w = (char*)d_ws;
  const size_t R  = 33554432ull;
  const long long WE = 4194304LL;   // 2048*2048 elems

  u16* xb  = (u16*)(w);
  u16* wT  = (u16*)(w + R);
  u16* wqT = wT;
  u16* woT = wT + 3 * WE;
  u16* q   = (u16*)(w + 2 * R);
  u16* kk  = (u16*)(w + 3 * R);
  u16* v   = (u16*)(w + 4 * R);
  u16* vT  = (u16*)(w + 5 * R);
  u16* o   = v;                      // v dead after transpose
  u16* attnx = xb;                   // xb dead after projections
  u16* slot0 = (u16*)d_out;          // 16.8M elems (4 batches x S x S bf16)
  u16* slot1 = slot0 + 16777216ull;  // second half of d_out

  const float sc0 = 1.0f / sqrtf(512.0f);
  const float sc1 = 1.0f / sqrtf(1024.0f);
  const float sc2 = 1.0f / sqrtf(1536.0f);
  const float sc3 = 1.0f / sqrtf(2048.0f);

  // allow 128 KB dynamic LDS on the big-tile GEMM (deterministic, capture-safe)
  hipFuncSetAttribute(reinterpret_cast<const void*>(&gemm256<true>),
                      hipFuncAttributeMaxDynamicSharedMemorySize, 131072);
  hipFuncSetAttribute(reinterpret_cast<const void*>(&gemm256<false>),
                      hipFuncAttributeMaxDynamicSharedMemorySize, 131072);

  // 1) x -> bf16; weights -> transposed bf16
  conv_f32_bf16<<<8192, 256, 0, stream>>>(x, xb);
  transpose_conv4<<<dim3(64, 64, 4), 256, 0, stream>>>(Wq, Wk, Wv, Wo, wT);
  // 2) fused q,k,v projection: M=8192, per-mat N=2048 (8 n-tiles = 8 XCDs), K=2048
  gemm256<true><<<dim3(768), 512, 131072, stream>>>(
      xb, 2048, wqT, 2048, q, 2048, 2048, 3, WE, 16777216LL);
  // 3) v -> vT
  transpose_bf16<<<dim3(64, 64, 4), 256, 0, stream>>>(v, vT);
  // 4) pass A: K=0..1024, snapshots -> slot0 (slice0), slot1 (slice1)
  qk_mega<<<dim3(16, 16, 4), 256, 0, stream>>>(q, kk, slot0, slot1, sc0, sc1,
                                               nullptr, 0.f);
  softmax_causal<<<dim3(2048, 4), 256, 0, stream>>>(slot0, slot0);
  gemm_nt<true><<<dim3(4, 16, 4), 256, 0, stream>>>(
      slot0, WE, 2048, vT, WE, 2048, o, WE, 2048, 2048, 2);
  softmax_causal<<<dim3(2048, 4), 256, 0, stream>>>(slot1, attnx);
  gemm_nt<true><<<dim3(4, 16, 4), 256, 0, stream>>>(
      attnx, WE, 2048, vT + 1048576, WE, 2048, o + 512, WE, 2048, 2048, 2);
  // 5) pass B: K=1024..2048, init from slot1 (* sqrt(1024)), snapshots slices 2,3
  qk_mega<<<dim3(16, 16, 4), 256, 0, stream>>>(q + 1024, kk + 1024, slot0, slot1,
                                               sc2, sc3, slot1, 32.0f);
  softmax_causal<<<dim3(2048, 4), 256, 0, stream>>>(slot0, slot0);
  gemm_nt<true><<<dim3(4, 16, 4), 256, 0, stream>>>(
      slot0, WE, 2048, vT + 2 * 1048576, WE, 2048, o + 1024, WE, 2048, 2048, 2);
  softmax_causal<<<dim3(2048, 4), 256, 0, stream>>>(slot1, slot1);
  gemm_nt<true><<<dim3(4, 16, 4), 256, 0, stream>>>(
      slot1, WE, 2048, vT + 3 * 1048576, WE, 2048, o + 1536, WE, 2048, 2048, 2);
  // 6) out = o @ Wo: M=8192, N=2048, K=2048
  gemm256<false><<<dim3(256), 512, 131072, stream>>>(
      o, 2048, woT, 2048, out, 2048, 2048, 1, 0LL, 0LL);
}

// Round 8
// 591.001 us; speedup vs baseline: 1.1050x; 1.0822x over previous
//
#include <hip/hip_runtime.h>

// MMHSA Matryoshka attention, B=4, S=2048, D=2048, slices {512,1024,1536,2048}.
// Big GEMMs: 256-wide-N tile bf16 MFMA kernel, ring-2 BK=32 LDS double-buffer
//   (64KB @ BMT=256 -> 2 blocks/CU; 48KB @ BMT=128 -> 2-3 blocks/CU),
//   reg-pipelined frags, per-tile {lgkm+bar; STG; 32 MFMA; vmcnt(0)+bar},
//   XOR bank-swizzle (0 conflicts measured), XCD-residency decode (FETCH -45%).
// Attention: 2-pass snapshot QK sweep + bf16 softmax (write-truncated) + merged PV.
//
// Workspace (R = 32 MiB, 6R = 201.3 MB):
//   [0,R):    xb (bf16 x)          -> attn scratch for slice 1
//   [R,2R):   wqT wkT wvT woT bf16
//   [2R,3R):  q   [3R,4R): k   [4R,5R): v -> o   [5R,6R): vT
// bf16 snapshots live in d_out (slot0/slot1) until the final GEMM.

typedef __attribute__((ext_vector_type(8))) short bf16x8;
typedef __attribute__((ext_vector_type(4))) float f32x4;
typedef unsigned short u16;
typedef unsigned int u32;

__device__ __forceinline__ u16 f2bf(float f) {
  union { float f; u32 u; } v; v.f = f;
  u32 r = v.u + 0x7fffu + ((v.u >> 16) & 1u);
  return (u16)(r >> 16);
}
__device__ __forceinline__ float bf2f(u16 b) {
  union { u32 u; float f; } v; v.u = ((u32)b) << 16;
  return v.f;
}
struct alignas(16) U16x8 { u16 v[8]; };

#define GLDS(gp, lp)                                                      \
  __builtin_amdgcn_global_load_lds(                                       \
      (const __attribute__((address_space(1))) void*)(gp),                \
      (__attribute__((address_space(3))) void*)(lp), 16, 0, 0)

// ---------------- conversion / transpose kernels ----------------

__global__ __launch_bounds__(256) void conv_f32_bf16(const float* __restrict__ in,
                                                     u16* __restrict__ out) {
  size_t i = ((size_t)blockIdx.x * 256 + threadIdx.x) * 8;
  float4 a = *(const float4*)(in + i);
  float4 b = *(const float4*)(in + i + 4);
  U16x8 w;
  w.v[0] = f2bf(a.x); w.v[1] = f2bf(a.y); w.v[2] = f2bf(a.z); w.v[3] = f2bf(a.w);
  w.v[4] = f2bf(b.x); w.v[5] = f2bf(b.y); w.v[6] = f2bf(b.z); w.v[7] = f2bf(b.w);
  *(U16x8*)(out + i) = w;
}

__global__ __launch_bounds__(256) void transpose_conv4(const float* __restrict__ W0,
                                                       const float* __restrict__ W1,
                                                       const float* __restrict__ W2,
                                                       const float* __restrict__ W3,
                                                       u16* __restrict__ out) {
  const int D = 2048;
  const float* in = (blockIdx.z == 0) ? W0 : (blockIdx.z == 1) ? W1
                  : (blockIdx.z == 2) ? W2 : W3;
  u16* o = out + (size_t)blockIdx.z * D * D;
  __shared__ float t[32][33];
  int bx = blockIdx.x * 32, by = blockIdx.y * 32;
  int tx = threadIdx.x & 31, ty = threadIdx.x >> 5;
#pragma unroll
  for (int i = 0; i < 32; i += 8)
    t[ty + i][tx] = in[(size_t)(by + ty + i) * D + bx + tx];
  __syncthreads();
#pragma unroll
  for (int i = 0; i < 32; i += 8)
    o[(size_t)(bx + ty + i) * D + by + tx] = f2bf(t[tx][ty + i]);
}

__global__ __launch_bounds__(256) void transpose_bf16(const u16* __restrict__ in,
                                                      u16* __restrict__ out) {
  const int D = 2048;
  size_t zoff = (size_t)blockIdx.z * D * D;
  in += zoff; out += zoff;
  __shared__ u16 t[32][34];
  int bx = blockIdx.x * 32, by = blockIdx.y * 32;
  int tx = threadIdx.x & 31, ty = threadIdx.x >> 5;
#pragma unroll
  for (int i = 0; i < 32; i += 8)
    t[ty + i][tx] = in[(size_t)(by + ty + i) * D + bx + tx];
  __syncthreads();
#pragma unroll
  for (int i = 0; i < 32; i += 8)
    out[(size_t)(bx + ty + i) * D + by + tx] = t[tx][ty + i];
}

// ===== BMTx256 ring-2 NT GEMM: C[M,N] = A[M,K] @ B[N,K]^T =====
// BMT=256: 512 thr, 8 waves (2Mx4N); BMT=128: 256 thr, 4 waves (1Mx4N).
// Per-wave output 128x64 (acc 8x4 f32x4). Ring-2 of BK=32 LDS slots.
// Per K-tile tt: READF(tt+1); lgkmcnt(12); barrier; STG(tt+2 -> slot tt&1);
//   sched_barrier; 32 MFMA on regs read last iter (setprio); vmcnt(0); barrier.
// LDS bank swizzle: 16B slot s at row r holds global slot s ^ ((r>>1)&3).
// Decode: XCD x owns n-tile x (N must be 2048); within XCD mat fastest, then m.
// Requires K%64==0, K/32>=4, M mult of BMT.
template <int BMT, bool OUT_BF16>
__global__ __launch_bounds__(BMT * 2, 2) void gemm256(
    const u16* __restrict__ A, int lda,
    const u16* __restrict__ B, int ldb,
    void* __restrict__ Cv, int ldc,
    int K, int nmat, long long sBm, long long sCm) {
  constexpr int NTH = BMT * 2;           // threads
  constexpr int RPS = NTH / 4;           // rows per load-step (128 or 64)
  constexpr int BSTEPS = 256 / RPS;      // B load-steps (2 or 4)
  constexpr int ASLOTB = BMT * 64;       // A slot bytes
  constexpr int BSLOTB = 16384;          // B slot bytes
  extern __shared__ char smem[];
  u16* const As = (u16*)smem;                       // 2 slots x BMT*32 u16
  u16* const Bs = (u16*)smem + 2 * BMT * 32;        // 2 slots x 8192 u16

  // XCD-residency decode: n-tile = XCD id; chunk = mat (fastest) x m-panel
  const u32 wg = blockIdx.x;
  const int n0 = (int)(wg & 7u) * 256;
  const u32 c = wg >> 3;
  const int mat = (int)(c % (u32)nmat);
  const int m0 = (int)(c / (u32)nmat) * BMT;

  B += (size_t)mat * sBm;

  const int tid = threadIdx.x;
  const int lane = tid & 63, wave = tid >> 6;
  const int wm = (wave >> 2) * 128;       // 0 or 128 (always 0 for BMT=128)
  const int wn = (wave & 3) * 64;
  const int fr = lane & 15, kgrp = lane >> 4;
  const u32 lo = (u32)(wave * 1024);      // wave-uniform LDS chunk for staging

  // staging map: thread covers LDS rows srow + j*RPS, 16B slot (tid&3);
  // pre-swizzled global source slot so LDS stays linear (rule #21)
  const int srow = tid >> 2;
  const int ssl = (tid & 3) ^ ((srow >> 1) & 3);
  const u16* gA = A + (size_t)(m0 + srow) * lda + ssl * 8;
  const u16* gB = B + (size_t)(n0 + srow) * ldb + ssl * 8;

  // ds_read swizzled k-offset (u16 units)
  const int koe = (kgrp ^ ((fr >> 1) & 3)) * 8;

#define STG(slot, kOff) do {                                              \
    char* la = (char*)As + (slot) * ASLOTB + lo;                          \
    char* lb = (char*)Bs + (slot) * BSLOTB + lo;                          \
    _Pragma("unroll") for (int j_ = 0; j_ < 2; ++j_)                      \
      GLDS(gA + (size_t)j_ * RPS * lda + (kOff), la + j_ * RPS * 64);     \
    _Pragma("unroll") for (int j_ = 0; j_ < BSTEPS; ++j_)                 \
      GLDS(gB + (size_t)j_ * RPS * ldb + (kOff), lb + j_ * RPS * 64);     \
  } while (0)

#define READF(FA, FB, sl) do {                                            \
    const u16* as_ = As + (sl) * (BMT * 32);                              \
    const u16* bs_ = Bs + (sl) * 8192;                                    \
    _Pragma("unroll") for (int n_ = 0; n_ < 4; ++n_)                      \
      FB[n_] = *(const bf16x8*)&bs_[((wn + n_ * 16 + fr) << 5) + koe];    \
    _Pragma("unroll") for (int m_ = 0; m_ < 8; ++m_)                      \
      FA[m_] = *(const bf16x8*)&as_[((wm + m_ * 16 + fr) << 5) + koe];    \
  } while (0)

#define MMCL(FA, FB) do {                                                 \
    __builtin_amdgcn_s_setprio(1);                                        \
    _Pragma("unroll") for (int m_ = 0; m_ < 8; ++m_)                      \
    _Pragma("unroll") for (int n_ = 0; n_ < 4; ++n_)                      \
      acc[m_][n_] = __builtin_amdgcn_mfma_f32_16x16x32_bf16(              \
          FA[m_], FB[n_], acc[m_][n_], 0, 0, 0);                          \
    __builtin_amdgcn_s_setprio(0);                                        \
  } while (0)

// Ring-2 K-tile: READF(tt+1) [certified by prev tail]; certify all waves'
// tile-tt reads done (lgkm<=12 + barrier); STG tile tt+2 over slot tt&1;
// MFMA(tt) hides STG latency; tail vmcnt(0)+barrier certifies tile tt+2.
#define ITER(tt, CA, CB, NA, NB) do {                                     \
    if ((tt) + 1 < NT) READF(NA, NB, ((tt) + 1) & 1);                     \
    if ((tt) + 2 < NT) {                                                  \
      asm volatile("s_waitcnt lgkmcnt(12)" ::: "memory");                 \
      __builtin_amdgcn_s_barrier();                                       \
      STG((tt) & 1, ((tt) + 2) * 32);                                     \
      __builtin_amdgcn_sched_barrier(0);                                  \
    }                                                                     \
    MMCL(CA, CB);                                                         \
    if ((tt) + 2 < NT) {                                                  \
      asm volatile("s_waitcnt vmcnt(0)" ::: "memory");                    \
      __builtin_amdgcn_s_barrier();                                       \
    }                                                                     \
  } while (0)

  f32x4 acc[8][4];
#pragma unroll
  for (int m = 0; m < 8; ++m)
#pragma unroll
    for (int n = 0; n < 4; ++n)
#pragma unroll
      for (int j = 0; j < 4; ++j) acc[m][n][j] = 0.f;

  const int NT = K >> 5;                  // even, >= 4
  bf16x8 fA0[8], fB0[4], fA1[8], fB1[4];

  // prologue: stage tiles 0,1; full drain; read tile-0 frags
  STG(0, 0);
  STG(1, 32);
  asm volatile("s_waitcnt vmcnt(0)" ::: "memory");
  __builtin_amdgcn_s_barrier();
  __builtin_amdgcn_sched_barrier(0);
  READF(fA0, fB0, 0);

  for (int tt = 0; tt < NT; tt += 2) {
    ITER(tt, fA0, fB0, fA1, fB1);
    ITER(tt + 1, fA1, fB1, fA0, fB0);
  }
#undef ITER
#undef MMCL
#undef READF
#undef STG

  // epilogue: C/D layout col = lane&15, row = (lane>>4)*4 + j
  const int cl = lane & 15, rb = (lane >> 4) * 4;
  if (OUT_BF16) {
    u16* C = (u16*)Cv + (size_t)mat * sCm;
#pragma unroll
    for (int m = 0; m < 8; ++m)
#pragma unroll
      for (int n = 0; n < 4; ++n)
#pragma unroll
        for (int j = 0; j < 4; ++j)
          C[(size_t)(m0 + wm + m * 16 + rb + j) * ldc + (n0 + wn + n * 16 + cl)] =
              f2bf(acc[m][n][j]);
  } else {
    float* C = (float*)Cv + (size_t)mat * sCm;
#pragma unroll
    for (int m = 0; m < 8; ++m)
#pragma unroll
      for (int n = 0; n < 4; ++n)
#pragma unroll
        for (int j = 0; j < 4; ++j)
          C[(size_t)(m0 + wm + m * 16 + rb + j) * ldc + (n0 + wn + n * 16 + cl)] =
              acc[m][n][j];
  }
}

// ---------------- staging macro for 128^2 kernels (128x32 bf16 tile) ----------------
#define STAGE4(Abuf, Bbuf, kOff)                                                       \
  do {                                                                                 \
    GLDS(ga0 + (kOff), (char*)(Abuf) + lo);                                            \
    GLDS(ga1 + (kOff), (char*)(Abuf) + lo + 4096);                                     \
    GLDS(gb0 + (kOff), (char*)(Bbuf) + lo);                                            \
    GLDS(gb1 + (kOff), (char*)(Bbuf) + lo + 4096);                                     \
  } while (0)

// ---------------- merged causal PV GEMM (128^2, m97 structure) ----------------
// z in [0,8): half = z>>2 selects A source (A0/A1) and slice s = s0+half.
// C[2048 x 512 cols of o] per (batch,slice); K truncated at m0+128.
__global__ __launch_bounds__(256) void gemm_pv(
    const u16* __restrict__ A0, const u16* __restrict__ A1,
    const u16* __restrict__ vT, u16* __restrict__ o, int s0) {
  const int z = blockIdx.z;
  const int half = z >> 2, b = z & 3, s = s0 + half;
  const u16* A = (half ? A1 : A0) + (size_t)b * 4194304ull;
  const u16* B = vT + (size_t)b * 4194304ull + (size_t)s * 512 * 2048;
  u16* C = o + (size_t)b * 4194304ull + s * 512;

  const int n0 = blockIdx.x * 128, m0 = blockIdx.y * 128;
  const int kEnd = m0 + 128;

  __shared__ alignas(16) u16 As[2][128 * 32];
  __shared__ alignas(16) u16 Bs[2][128 * 32];

  const int tid = threadIdx.x;
  const int lane = tid & 63, wave = tid >> 6;
  const int wm = (wave >> 1) * 64, wn = (wave & 1) * 64;
  const int fr = lane & 15, kc = (lane >> 4) * 8;

  const u16* ga0 = A + (size_t)(m0 + (tid >> 2)) * 2048 + (tid & 3) * 8;
  const u16* ga1 = ga0 + (size_t)64 * 2048;
  const u16* gb0 = B + (size_t)(n0 + (tid >> 2)) * 2048 + (tid & 3) * 8;
  const u16* gb1 = gb0 + (size_t)64 * 2048;
  const u32 lo = (u32)(wave * 1024);

  f32x4 acc[4][4];
#pragma unroll
  for (int m = 0; m < 4; ++m)
#pragma unroll
    for (int n = 0; n < 4; ++n)
#pragma unroll
      for (int j = 0; j < 4; ++j) acc[m][n][j] = 0.f;

  const int nt = kEnd >> 5;
  STAGE4(&As[0][0], &Bs[0][0], 0);
  for (int t = 0; t < nt; ++t) {
    __syncthreads();
    if (t + 1 < nt) STAGE4(&As[(t + 1) & 1][0], &Bs[(t + 1) & 1][0], (t + 1) * 32);
    const u16* as = &As[t & 1][0];
    const u16* bs = &Bs[t & 1][0];
    bf16x8 af[4], bfr[4];
#pragma unroll
    for (int m = 0; m < 4; ++m)
      af[m] = *(const bf16x8*)&as[(wm + m * 16 + fr) * 32 + kc];
#pragma unroll
    for (int n = 0; n < 4; ++n)
      bfr[n] = *(const bf16x8*)&bs[(wn + n * 16 + fr) * 32 + kc];
#pragma unroll
    for (int m = 0; m < 4; ++m)
#pragma unroll
      for (int n = 0; n < 4; ++n)
        acc[m][n] = __builtin_amdgcn_mfma_f32_16x16x32_bf16(af[m], bfr[n],
                                                            acc[m][n], 0, 0, 0);
  }

  const int col = lane & 15, rb = (lane >> 4) * 4;
#pragma unroll
  for (int m = 0; m < 4; ++m)
#pragma unroll
    for (int n = 0; n < 4; ++n)
#pragma unroll
      for (int j = 0; j < 4; ++j)
        C[(size_t)(m0 + wm + m * 16 + rb + j) * 2048 + (n0 + wn + n * 16 + col)] =
            f2bf(acc[m][n][j]);
}

// ---------------- snapshot QK sweep (K=1024 per pass, 128^2 tiles) ----------------
__global__ __launch_bounds__(256) void qk_mega(
    const u16* __restrict__ A, const u16* __restrict__ B,
    u16* __restrict__ snapA, u16* __restrict__ snapB,
    float scaleA, float scaleB,
    const u16* __restrict__ initSrc, float initScale) {
  const int lda = 2048;
  const int m0 = blockIdx.y * 128, n0 = blockIdx.x * 128;
  if (n0 >= m0 + 128) return;  // fully masked tile
  const size_t zWE = (size_t)blockIdx.z * 4194304ull;

  __shared__ alignas(16) u16 As[2][128 * 32];
  __shared__ alignas(16) u16 Bs[2][128 * 32];

  const int tid = threadIdx.x;
  const int lane = tid & 63, wave = tid >> 6;
  const int wm = (wave >> 1) * 64, wn = (wave & 1) * 64;
  const int fr = lane & 15, kc = (lane >> 4) * 8;
  const int col = lane & 15, rb = (lane >> 4) * 4;

  const u16* ga0 = A + zWE + (size_t)(m0 + (tid >> 2)) * lda + (tid & 3) * 8;
  const u16* ga1 = ga0 + (size_t)64 * lda;
  const u16* gb0 = B + zWE + (size_t)(n0 + (tid >> 2)) * lda + (tid & 3) * 8;
  const u16* gb1 = gb0 + (size_t)64 * lda;
  const u32 lo = (u32)(wave * 1024);

  f32x4 acc[4][4];
  if (initSrc) {
    const u16* ip = initSrc + zWE;
#pragma unroll
    for (int m = 0; m < 4; ++m)
#pragma unroll
      for (int n = 0; n < 4; ++n)
#pragma unroll
        for (int j = 0; j < 4; ++j)
          acc[m][n][j] = bf2f(ip[(size_t)(m0 + wm + m * 16 + rb + j) * 2048 +
                                 (n0 + wn + n * 16 + col)]) * initScale;
  } else {
#pragma unroll
    for (int m = 0; m < 4; ++m)
#pragma unroll
      for (int n = 0; n < 4; ++n)
#pragma unroll
        for (int j = 0; j < 4; ++j) acc[m][n][j] = 0.f;
  }

#define SNAPW(ptr, scl)                                                                \
  do {                                                                                 \
    u16* sp = (ptr) + zWE;                                                             \
    _Pragma("unroll") for (int m = 0; m < 4; ++m)                                      \
    _Pragma("unroll") for (int n = 0; n < 4; ++n)                                      \
    _Pragma("unroll") for (int j = 0; j < 4; ++j)                                      \
        sp[(size_t)(m0 + wm + m * 16 + rb + j) * 2048 + (n0 + wn + n * 16 + col)] =    \
            f2bf(acc[m][n][j] * (scl));                                                \
  } while (0)

  STAGE4(&As[0][0], &Bs[0][0], 0);
  for (int t = 0; t < 32; ++t) {
    __syncthreads();
    if (t + 1 < 32) STAGE4(&As[(t + 1) & 1][0], &Bs[(t + 1) & 1][0], (t + 1) * 32);
    const u16* as = &As[t & 1][0];
    const u16* bs = &Bs[t & 1][0];
    bf16x8 af[4], bfr[4];
#pragma unroll
    for (int m = 0; m < 4; ++m)
      af[m] = *(const bf16x8*)&as[(wm + m * 16 + fr) * 32 + kc];
#pragma unroll
    for (int n = 0; n < 4; ++n)
      bfr[n] = *(const bf16x8*)&bs[(wn + n * 16 + fr) * 32 + kc];
#pragma unroll
    for (int m = 0; m < 4; ++m)
#pragma unroll
      for (int n = 0; n < 4; ++n)
        acc[m][n] = __builtin_amdgcn_mfma_f32_16x16x32_bf16(af[m], bfr[n],
                                                            acc[m][n], 0, 0, 0);
    if (t == 15) SNAPW(snapA, scaleA);  // K=512 prefix done
  }
  SNAPW(snapB, scaleB);
#undef SNAPW
}

// ---------------- causal row softmax on scaled bf16 logits ----------------
// Writes only cols [0, roundup128(r+1)) — PV never reads beyond its kEnd.
__global__ __launch_bounds__(256) void softmax_causal(const u16* __restrict__ in,
                                                      u16* __restrict__ out) {
  const int S = 2048;
  const size_t WEz = (size_t)S * S * blockIdx.y;
  const int r = blockIdx.x;
  const int tid = threadIdx.x;
  const int lane = tid & 63, wave = tid >> 6;
  const int c0 = tid * 8;
  const int nvalid = r + 1;
  const int nwrite = (r & ~127) + 128;
  const u16* rowp = in + WEz + (size_t)r * S;

  float x[8];
  if (c0 < nvalid) {
    U16x8 a = *(const U16x8*)(rowp + c0);
#pragma unroll
    for (int i = 0; i < 8; ++i) x[i] = bf2f(a.v[i]);
  } else {
#pragma unroll
    for (int i = 0; i < 8; ++i) x[i] = 0.f;
  }

  float mx = -3e38f;
#pragma unroll
  for (int i = 0; i < 8; ++i)
    if (c0 + i < nvalid) mx = fmaxf(mx, x[i]);
#pragma unroll
  for (int off = 32; off > 0; off >>= 1) mx = fmaxf(mx, __shfl_xor(mx, off));
  __shared__ float redm[4], reds[4];
  if (lane == 0) redm[wave] = mx;
  __syncthreads();
  mx = fmaxf(fmaxf(redm[0], redm[1]), fmaxf(redm[2], redm[3]));

  float e[8], sum = 0.f;
#pragma unroll
  for (int i = 0; i < 8; ++i) {
    e[i] = (c0 + i < nvalid) ? __expf(x[i] - mx) : 0.f;
    sum += e[i];
  }
#pragma unroll
  for (int off = 32; off > 0; off >>= 1) sum += __shfl_xor(sum, off);
  if (lane == 0) reds[wave] = sum;
  __syncthreads();
  sum = reds[0] + reds[1] + reds[2] + reds[3];
  float inv = 1.f / sum;

  if (c0 < nwrite) {
    U16x8 w;
#pragma unroll
    for (int i = 0; i < 8; ++i) w.v[i] = f2bf(e[i] * inv);
    *(U16x8*)(out + WEz + (size_t)r * S + c0) = w;
  }
}

// ---------------- launcher ----------------
extern "C" void kernel_launch(void* const* d_in, const int* in_sizes, int n_in,
                              void* d_out, int out_size, void* d_ws, size_t ws_size,
                              hipStream_t stream) {
  (void)in_sizes; (void)n_in; (void)out_size; (void)ws_size;
  const float* x  = (const float*)d_in[0];
  // d_in[1] is the boolean causal mask; causality is hard-coded.
  const float* Wq = (const float*)d_in[2];
  const float* Wk = (const float*)d_in[3];
  const float* Wv = (const float*)d_in[4];
  const float* Wo = (const float*)d_in[5];
  float* out = (float*)d_out;

  char* w = (char*)d_ws;
  const size_t R  = 33554432ull;
  const long long WE = 4194304LL;   // 2048*2048 elems

  u16* xb  = (u16*)(w);
  u16* wT  = (u16*)(w + R);
  u16* wqT = wT;
  u16* woT = wT + 3 * WE;
  u16* q   = (u16*)(w + 2 * R);
  u16* kk  = (u16*)(w + 3 * R);
  u16* v   = (u16*)(w + 4 * R);
  u16* vT  = (u16*)(w + 5 * R);
  u16* o   = v;                      // v dead after transpose
  u16* attnx = xb;                   // xb dead after projections
  u16* slot0 = (u16*)d_out;          // 16.8M elems (4 batches x S x S bf16)
  u16* slot1 = slot0 + 16777216ull;  // second half of d_out

  const float sc0 = 1.0f / sqrtf(512.0f);
  const float sc1 = 1.0f / sqrtf(1024.0f);
  const float sc2 = 1.0f / sqrtf(1536.0f);
  const float sc3 = 1.0f / sqrtf(2048.0f);

  // allow dynamic LDS (deterministic, capture-safe)
  hipFuncSetAttribute(reinterpret_cast<const void*>(&gemm256<256, true>),
                      hipFuncAttributeMaxDynamicSharedMemorySize, 65536);
  hipFuncSetAttribute(reinterpret_cast<const void*>(&gemm256<128, false>),
                      hipFuncAttributeMaxDynamicSharedMemorySize, 49152);

  // 1) x -> bf16; weights -> transposed bf16
  conv_f32_bf16<<<8192, 256, 0, stream>>>(x, xb);
  transpose_conv4<<<dim3(64, 64, 4), 256, 0, stream>>>(Wq, Wk, Wv, Wo, wT);
  // 2) fused q,k,v projection: M=8192, per-mat N=2048 (8 n-tiles = 8 XCDs), K=2048
  gemm256<256, true><<<dim3(768), 512, 65536, stream>>>(
      xb, 2048, wqT, 2048, q, 2048, 2048, 3, WE, 16777216LL);
  // 3) v -> vT
  transpose_bf16<<<dim3(64, 64, 4), 256, 0, stream>>>(v, vT);
  // 4) pass A: K=0..1024, snapshots -> slot0 (slice0), slot1 (slice1)
  qk_mega<<<dim3(16, 16, 4), 256, 0, stream>>>(q, kk, slot0, slot1, sc0, sc1,
                                               nullptr, 0.f);
  softmax_causal<<<dim3(2048, 4), 256, 0, stream>>>(slot0, slot0);
  softmax_causal<<<dim3(2048, 4), 256, 0, stream>>>(slot1, attnx);
  gemm_pv<<<dim3(4, 16, 8), 256, 0, stream>>>(slot0, attnx, vT, o, 0);
  // 5) pass B: K=1024..2048, init from slot1 (* sqrt(1024)), snapshots slices 2,3
  qk_mega<<<dim3(16, 16, 4), 256, 0, stream>>>(q + 1024, kk + 1024, slot0, slot1,
                                               sc2, sc3, slot1, 32.0f);
  softmax_causal<<<dim3(2048, 4), 256, 0, stream>>>(slot0, slot0);
  softmax_causal<<<dim3(2048, 4), 256, 0, stream>>>(slot1, slot1);
  gemm_pv<<<dim3(4, 16, 8), 256, 0, stream>>>(slot0, slot1, vT, o, 2);
  // 6) out = o @ Wo: M=8192 (64 m-tiles of 128), N=2048, K=2048
  gemm256<128, false><<<dim3(512), 256, 49152, stream>>>(
      o, 2048, woT, 2048, out, 2048, 2048, 1, 0LL, 0LL);
}